// Round 8
// baseline (393.352 us; speedup 1.0000x reference)
//
#include <hip/hip_runtime.h>
#include <math.h>

#define NEG_SLOPE 0.2f
#define BN_EPS 1e-5f

typedef __attribute__((ext_vector_type(8))) short short8;     // 8 bf16 (4 VGPRs)
typedef __attribute__((ext_vector_type(4))) float f32x4;

__device__ __forceinline__ float lrelu_f(float x){ return x > 0.f ? x : NEG_SLOPE * x; }
__device__ __forceinline__ float elu_f(float x){ return x > 0.f ? x : __expf(x) - 1.f; }

// float -> bf16 (round-to-nearest-even), and unpack helpers
__device__ __forceinline__ unsigned short f2bf(float f){
    unsigned u = __float_as_uint(f);
    return (unsigned short)((u + 0x7fffu + ((u >> 16) & 1u)) >> 16);
}
__device__ __forceinline__ float bf_lo(unsigned v){ return __uint_as_float(v << 16); }
__device__ __forceinline__ float bf_hi(unsigned v){ return __uint_as_float(v & 0xffff0000u); }
__device__ __forceinline__ float bf2f(unsigned short b){ return __uint_as_float((unsigned)b << 16); }

// ordered-uint encoding for float atomicMax
__device__ __forceinline__ unsigned enc_f(float x){
    unsigned b = __float_as_uint(x);
    return (b & 0x80000000u) ? ~b : (b | 0x80000000u);
}
__device__ __forceinline__ float dec_f(unsigned u){
    return __uint_as_float((u & 0x80000000u) ? (u & 0x7FFFFFFFu) : ~u);
}

// ---------- CSR build ----------
__global__ void k_count(const int* __restrict__ ei, int E0, int N, int* __restrict__ counts){
    int i = blockIdx.x * blockDim.x + threadIdx.x;
    int tot = E0 + N;
    if (i >= tot) return;
    int dst = (i < E0) ? ei[E0 + i] : (i - E0);
    atomicAdd(&counts[dst], 1);
}

__global__ void k_scan_part(const int* __restrict__ counts, int n, int* __restrict__ part){
    __shared__ int sh[256];
    int tid = threadIdx.x;
    int i = blockIdx.x * 256 + tid;
    int v = (i < n) ? counts[i] : 0;
    sh[tid] = v;
    __syncthreads();
    for (int o = 128; o > 0; o >>= 1){
        if (tid < o) sh[tid] += sh[tid + o];
        __syncthreads();
    }
    if (tid == 0) part[blockIdx.x] = sh[0];
}

__global__ void k_scan_top(int* __restrict__ part, int P, int n, int* __restrict__ row_ptr){
    __shared__ int sh[256];
    int tid = threadIdx.x;
    int v = (tid < P) ? part[tid] : 0;
    sh[tid] = v;
    __syncthreads();
    for (int o = 1; o < 256; o <<= 1){
        int t = (tid >= o) ? sh[tid - o] : 0;
        __syncthreads();
        sh[tid] += t;
        __syncthreads();
    }
    if (tid < P) part[tid] = sh[tid] - v;
    if (tid == 0) row_ptr[n] = sh[255];
}

__global__ void k_scan_write(const int* __restrict__ counts, const int* __restrict__ part,
                             int n, int* __restrict__ row_ptr){
    __shared__ int sh[256];
    int tid = threadIdx.x;
    int i = blockIdx.x * 256 + tid;
    int v = (i < n) ? counts[i] : 0;
    sh[tid] = v;
    __syncthreads();
    for (int o = 1; o < 256; o <<= 1){
        int t = (tid >= o) ? sh[tid - o] : 0;
        __syncthreads();
        sh[tid] += t;
        __syncthreads();
    }
    if (i < n) row_ptr[i] = part[blockIdx.x] + sh[tid] - v;
}

__global__ void k_scatter(const int* __restrict__ ei, int E0, int N,
                          const int* __restrict__ row_ptr, int* __restrict__ cursor,
                          int* __restrict__ csr_src){
    int i = blockIdx.x * blockDim.x + threadIdx.x;
    int tot = E0 + N;
    if (i >= tot) return;
    int src, dst;
    if (i < E0){ src = ei[i]; dst = ei[E0 + i]; } else { src = dst = i - E0; }
    int pos = atomicAdd(&cursor[dst], 1);
    csr_src[row_ptr[dst] + pos] = src;
}

__global__ void k_graph_ptr(const int* __restrict__ batch, int N, int G, int* __restrict__ gp){
    int i = blockIdx.x * blockDim.x + threadIdx.x;
    if (i >= N) return;
    int b = batch[i];
    if (i == 0){ for (int g = 0; g <= b; ++g) gp[g] = 0; }
    else { int pb = batch[i - 1]; for (int g = pb + 1; g <= b; ++g) gp[g] = i; }
    if (i == N - 1){ for (int g = b + 1; g <= G; ++g) gp[g] = N; }
}

// ---------- W prep: fp32 [128][OUT] -> bf16 transposed [OUT][128] ----------
__global__ void k_wprep(const float* __restrict__ W, int OUT, unsigned short* __restrict__ Wt){
    int i = blockIdx.x * 256 + threadIdx.x;
    if (i >= 128 * OUT) return;
    int k = i / OUT, c = i % OUT;
    Wt[c * 128 + k] = f2bf(W[i]);
}

// ---------- layer 1 GEMM (IN=5 -> OUT=128, H=4) + attention dots; h stored bf16 ----------
__global__ void k_gemm1(const float* __restrict__ X, const float* __restrict__ W,
                        const float* __restrict__ atts, const float* __restrict__ attd,
                        unsigned short* __restrict__ h, float* __restrict__ as_,
                        float* __restrict__ ad_, int N){
    __shared__ float Wl[5 * 128];
    int tid = threadIdx.x;
    for (int i = tid; i < 5 * 128; i += 256) Wl[i] = W[i];
    __syncthreads();
    int c = tid & 127, local = tid >> 7;
    float as_c = atts[c], ad_c = attd[c];
    for (long node = (long)blockIdx.x * 2 + local; node < N; node += (long)gridDim.x * 2){
        float x0 = X[node * 5 + 0], x1 = X[node * 5 + 1], x2 = X[node * 5 + 2],
              x3 = X[node * 5 + 3], x4 = X[node * 5 + 4];
        float acc = x0 * Wl[c] + x1 * Wl[128 + c] + x2 * Wl[256 + c] +
                    x3 * Wl[384 + c] + x4 * Wl[512 + c];
        float vs = acc * as_c, vd = acc * ad_c;
#pragma unroll
        for (int m = 1; m < 32; m <<= 1){ vs += __shfl_xor(vs, m); vd += __shfl_xor(vd, m); }
        h[node * 128 + c] = f2bf(acc);
        if ((c & 31) == 0){ as_[node * 4 + (c >> 5)] = vs; ad_[node * 4 + (c >> 5)] = vd; }
    }
}

// ---------- MFMA GEMM (IN=128 -> OUT, H heads), fused BN+ELU on X, bf16 in, fp32 acc ----------
template<int OUT, int H, bool BN>
__launch_bounds__(256)
__global__ void k_gemm_mfma(const float* __restrict__ X, const unsigned short* __restrict__ Wt,
                            const float* __restrict__ atts, const float* __restrict__ attd,
                            const float* __restrict__ coefs, const float* __restrict__ coefb,
                            unsigned short* __restrict__ h, float* __restrict__ as_,
                            float* __restrict__ ad_, int N){
    constexpr int TM  = 64;
    constexpr int NCT = OUT / 16;
    constexpr int CPH = NCT / H;
    __shared__ unsigned short Xl[TM * 128];
    __shared__ unsigned short Wl[OUT * 128];
    int tid = threadIdx.x;
    long base = (long)blockIdx.x * TM;

    for (int i = tid; i < OUT * 16; i += 256){
        int r = i >> 4, g = i & 15;
        uint4 v = *(const uint4*)&Wt[r * 128 + g * 8];
        int gs = g ^ (r & 7);
        *(uint4*)&Wl[r * 128 + gs * 8] = v;
    }
    for (int i = tid; i < TM * 16; i += 256){
        int r = i >> 4, g = i & 15;
        long node = base + r;
        uint4 o;
        if (node < N){
            const float* xp = &X[node * 128 + g * 8];
            float f[8];
            *(float4*)&f[0] = *(const float4*)xp;
            *(float4*)&f[4] = *(const float4*)(xp + 4);
#pragma unroll
            for (int j = 0; j < 8; ++j){
                float v = f[j];
                if (BN) v = elu_f(fmaf(v, coefs[g * 8 + j], coefb[g * 8 + j]));
                f[j] = v;
            }
            o.x = (unsigned)f2bf(f[0]) | ((unsigned)f2bf(f[1]) << 16);
            o.y = (unsigned)f2bf(f[2]) | ((unsigned)f2bf(f[3]) << 16);
            o.z = (unsigned)f2bf(f[4]) | ((unsigned)f2bf(f[5]) << 16);
            o.w = (unsigned)f2bf(f[6]) | ((unsigned)f2bf(f[7]) << 16);
        } else {
            o.x = o.y = o.z = o.w = 0u;
        }
        int gs = g ^ (r & 7);
        *(uint4*)&Xl[r * 128 + gs * 8] = o;
    }
    __syncthreads();

    int wid = tid >> 6;
    int lane = tid & 63;
    int lr = lane & 15, lk = lane >> 4;

    short8 afrag[4];
    int arow = wid * 16 + lr;
#pragma unroll
    for (int ks = 0; ks < 4; ++ks){
        int g = ks * 4 + lk;
        int gs = g ^ (arow & 7);
        afrag[ks] = *(const short8*)&Xl[arow * 128 + gs * 8];
    }
    f32x4 acc[NCT];
#pragma unroll
    for (int ct = 0; ct < NCT; ++ct) acc[ct] = (f32x4){0.f, 0.f, 0.f, 0.f};
#pragma unroll
    for (int ct = 0; ct < NCT; ++ct){
        int brow = ct * 16 + lr;
#pragma unroll
        for (int ks = 0; ks < 4; ++ks){
            int g = ks * 4 + lk;
            int gs = g ^ (brow & 7);
            short8 bfrag = *(const short8*)&Wl[brow * 128 + gs * 8];
            acc[ct] = __builtin_amdgcn_mfma_f32_16x16x32_bf16(afrag[ks], bfrag, acc[ct], 0, 0, 0);
        }
    }
    float ps[H][4], pd[H][4];
#pragma unroll
    for (int hh = 0; hh < H; ++hh)
#pragma unroll
        for (int j = 0; j < 4; ++j){ ps[hh][j] = 0.f; pd[hh][j] = 0.f; }
#pragma unroll
    for (int ct = 0; ct < NCT; ++ct){
        int col = ct * 16 + lr;
        int hh = ct / CPH;
        float asv = atts[col], adv = attd[col];
#pragma unroll
        for (int j = 0; j < 4; ++j){
            float v = acc[ct][j];
            long node = base + wid * 16 + lk * 4 + j;
            if (node < N) h[node * OUT + col] = f2bf(v);
            ps[hh][j] += v * asv;
            pd[hh][j] += v * adv;
        }
    }
#pragma unroll
    for (int m = 1; m < 16; m <<= 1){
#pragma unroll
        for (int hh = 0; hh < H; ++hh)
#pragma unroll
            for (int j = 0; j < 4; ++j){
                ps[hh][j] += __shfl_xor(ps[hh][j], m);
                pd[hh][j] += __shfl_xor(pd[hh][j], m);
            }
    }
    if (lr == 0){
#pragma unroll
        for (int j = 0; j < 4; ++j){
            long node = base + wid * 16 + lk * 4 + j;
            if (node < N){
#pragma unroll
                for (int hh = 0; hh < H; ++hh){
                    as_[node * H + hh] = ps[hh][j];
                    ad_[node * H + hh] = pd[hh][j];
                }
            }
        }
    }
}

// ---------- GAT aggregation ----------
template<int C, int H, int ACT>
__global__ void k_agg(const unsigned short* __restrict__ h, const float* __restrict__ as_,
                      const float* __restrict__ ad_, const int* __restrict__ row_ptr,
                      const int* __restrict__ csr_src, const float* __restrict__ bias,
                      float* __restrict__ out, int N){
    constexpr int CPL = C / 64;
    constexpr int GROUP = C / H;
    int n = blockIdx.x;
    if (n >= N) return;
    int lane = threadIdx.x;
    int hh = (CPL * lane) / GROUP;
    float ad = ad_[n * H + hh];
    int beg = row_ptr[n], end = row_ptr[n + 1];
    float accx = 0.f, accy = 0.f, dn = 0.f;
    const unsigned* h32 = (const unsigned*)h;
    int e = beg;
    for (; e + 2 <= end; e += 2){
        int s0 = csr_src[e], s1 = csr_src[e + 1];
        float a0 = as_[s0 * H + hh], a1 = as_[s1 * H + hh];
        unsigned v0, v1; unsigned short w0, w1;
        if (CPL == 2){ v0 = h32[(long)s0 * 64 + lane]; v1 = h32[(long)s1 * 64 + lane]; }
        else { w0 = h[(long)s0 * 64 + lane]; w1 = h[(long)s1 * 64 + lane]; }
        float p0 = __expf(lrelu_f(a0 + ad));
        float p1 = __expf(lrelu_f(a1 + ad));
        dn += p0 + p1;
        if (CPL == 2){
            accx += p0 * bf_lo(v0) + p1 * bf_lo(v1);
            accy += p0 * bf_hi(v0) + p1 * bf_hi(v1);
        } else {
            accx += p0 * bf2f(w0) + p1 * bf2f(w1);
        }
    }
    if (e < end){
        int s0 = csr_src[e];
        float p0 = __expf(lrelu_f(as_[s0 * H + hh] + ad));
        dn += p0;
        if (CPL == 2){
            unsigned v0 = h32[(long)s0 * 64 + lane];
            accx += p0 * bf_lo(v0); accy += p0 * bf_hi(v0);
        } else {
            accx += p0 * bf2f(h[(long)s0 * 64 + lane]);
        }
    }
    float inv = 1.f / dn;
    if (CPL == 2){
        float vx = accx * inv + bias[2 * lane];
        float vy = accy * inv + bias[2 * lane + 1];
        if (ACT == 1){ vx = elu_f(vx); vy = elu_f(vy); }
        float2 o; o.x = vx; o.y = vy;
        *(float2*)&out[(long)n * C + 2 * lane] = o;
    } else {
        float v = accx * inv + bias[lane];
        if (ACT == 1) v = elu_f(v);
        out[(long)n * C + lane] = v;
    }
}

// ---------- BatchNorm stats v2: 1024-thr blocks, float4 loads, LDS tree, ticketed coef ----------
__launch_bounds__(1024)
__global__ void k_bn_stats(const float* __restrict__ x, int N,
                           float* __restrict__ sums, float* __restrict__ sumsq,
                           int* __restrict__ ticket,
                           const float* __restrict__ g, const float* __restrict__ be,
                           float invN, float* __restrict__ cs, float* __restrict__ cb){
    __shared__ float4 ls[1024], lq[1024];
    __shared__ int lastdone;
    int tid = threadIdx.x;
    int cq = tid & 31;          // channel quad: channels cq*4..cq*4+3
    int rg = tid >> 5;          // row group 0..31
    float4 s = {0.f, 0.f, 0.f, 0.f}, q = {0.f, 0.f, 0.f, 0.f};
    int stride = gridDim.x * 32;
    for (long r = (long)blockIdx.x * 32 + rg; r < N; r += stride){
        float4 v = *(const float4*)&x[r * 128 + cq * 4];
        s.x += v.x; s.y += v.y; s.z += v.z; s.w += v.w;
        q.x += v.x * v.x; q.y += v.y * v.y; q.z += v.z * v.z; q.w += v.w * v.w;
    }
    ls[tid] = s; lq[tid] = q;
    __syncthreads();
    for (int o = 16; o > 0; o >>= 1){
        if (rg < o){
            float4 s2 = ls[tid + o * 32], q2 = lq[tid + o * 32];
            s.x += s2.x; s.y += s2.y; s.z += s2.z; s.w += s2.w;
            q.x += q2.x; q.y += q2.y; q.z += q2.z; q.w += q2.w;
            ls[tid] = s; lq[tid] = q;
        }
        __syncthreads();
    }
    if (rg == 0){
        atomicAdd(&sums[cq * 4 + 0], s.x); atomicAdd(&sums[cq * 4 + 1], s.y);
        atomicAdd(&sums[cq * 4 + 2], s.z); atomicAdd(&sums[cq * 4 + 3], s.w);
        atomicAdd(&sumsq[cq * 4 + 0], q.x); atomicAdd(&sumsq[cq * 4 + 1], q.y);
        atomicAdd(&sumsq[cq * 4 + 2], q.z); atomicAdd(&sumsq[cq * 4 + 3], q.w);
    }
    __threadfence();
    if (tid == 0) lastdone = atomicAdd(ticket, 1);
    __syncthreads();
    if (lastdone == gridDim.x - 1 && tid < 128){
        float su = atomicAdd(&sums[tid], 0.f);
        float sq = atomicAdd(&sumsq[tid], 0.f);
        float mu = su * invN;
        float var = sq * invN - mu * mu;
        float sc = g[tid] * rsqrtf(var + BN_EPS);
        cs[tid] = sc;
        cb[tid] = be[tid] - mu * sc;
    }
}

// ---------- pooling ----------
__global__ void k_pool_part(const float* __restrict__ x, const int* __restrict__ gp,
                            float* __restrict__ psum, unsigned* __restrict__ pmax){
    constexpr int S = 16;
    __shared__ float ssum[256], smax[256];
    int g = blockIdx.y;
    int split = blockIdx.x;
    int tid = threadIdx.x;
    int c = tid & 63, sub = tid >> 6;
    int beg = gp[g], end = gp[g + 1];
    int len = end - beg;
    int chunk = (len + S - 1) / S;
    int lo = beg + split * chunk;
    int hi = lo + chunk; if (hi > end) hi = end;
    if (lo >= hi) return;
    float s = 0.f, mx = -1e30f;
    for (int i = lo + sub; i < hi; i += 4){
        float v = x[(long)i * 64 + c];
        s += v; mx = fmaxf(mx, v);
    }
    ssum[tid] = s; smax[tid] = mx;
    __syncthreads();
    if (tid < 64){
        for (int k = 1; k < 4; ++k){ s += ssum[tid + 64 * k]; mx = fmaxf(mx, smax[tid + 64 * k]); }
        atomicAdd(&psum[g * 64 + c], s);
        atomicMax(&pmax[g * 64 + c], enc_f(mx));
    }
}

__global__ void k_pool_fin(const float* __restrict__ psum, const unsigned* __restrict__ pmax,
                           const int* __restrict__ gp, float* __restrict__ out){
    int g = blockIdx.x;
    int c = threadIdx.x;
    int cnt = gp[g + 1] - gp[g];
    float mean = (cnt > 0) ? psum[g * 64 + c] / (float)cnt : 0.f;
    float mx   = (cnt > 0) ? dec_f(pmax[g * 64 + c]) : 0.f;
    out[g * 128 + c]      = mean;
    out[g * 128 + 64 + c] = mx;
}

extern "C" void kernel_launch(void* const* d_in, const int* in_sizes, int n_in,
                              void* d_out, int out_size, void* d_ws, size_t ws_size,
                              hipStream_t stream){
    const float* x   = (const float*)d_in[0];
    const int*   ei  = (const int*)d_in[1];
    const int*   bat = (const int*)d_in[2];
    const float* W1  = (const float*)d_in[3];
    const float* a1s = (const float*)d_in[4];
    const float* a1d = (const float*)d_in[5];
    const float* b1  = (const float*)d_in[6];
    const float* g1  = (const float*)d_in[7];
    const float* be1 = (const float*)d_in[8];
    const float* W2  = (const float*)d_in[9];
    const float* a2s = (const float*)d_in[10];
    const float* a2d = (const float*)d_in[11];
    const float* b2  = (const float*)d_in[12];
    const float* g2  = (const float*)d_in[13];
    const float* be2 = (const float*)d_in[14];
    const float* W3  = (const float*)d_in[15];
    const float* a3s = (const float*)d_in[16];
    const float* a3d = (const float*)d_in[17];
    const float* b3  = (const float*)d_in[18];
    float* out = (float*)d_out;

    int N  = in_sizes[2];        // 50000
    int E0 = in_sizes[1] / 2;    // 600000
    int E  = E0 + N;
    const int G = 64;
    int P  = (N + 255) / 256;

    char* ws = (char*)d_ws;
    size_t off = 0;
    auto alloc = [&](size_t bytes) -> char* {
        char* p = ws + off;
        off += (bytes + 255) & ~(size_t)255;
        return p;
    };
    // --- zero-init region ---
    int*      counts  = (int*)alloc((size_t)N * 4);
    int*      cursor  = (int*)alloc((size_t)N * 4);
    float*    sums1   = (float*)alloc(128 * 4);
    float*    sumsq1  = (float*)alloc(128 * 4);
    float*    sums2   = (float*)alloc(128 * 4);
    float*    sumsq2  = (float*)alloc(128 * 4);
    int*      tick1   = (int*)alloc(4);
    int*      tick2   = (int*)alloc(4);
    float*    psum    = (float*)alloc((size_t)G * 64 * 4);
    unsigned* pmax    = (unsigned*)alloc((size_t)G * 64 * 4);
    size_t zero_bytes = off;
    // --- rest ---
    int*   part    = (int*)alloc(256 * 4);
    int*   row_ptr = (int*)alloc((size_t)(N + 1) * 4);
    int*   csr     = (int*)alloc((size_t)E * 4);
    int*   gp      = (int*)alloc((size_t)(G + 1) * 4);
    float* as_buf  = (float*)alloc((size_t)N * 4 * 4);
    float* ad_buf  = (float*)alloc((size_t)N * 4 * 4);
    float* coefs   = (float*)alloc(128 * 4);
    float* coefb   = (float*)alloc(128 * 4);
    unsigned short* wt2 = (unsigned short*)alloc(128 * 128 * 2);
    unsigned short* wt3 = (unsigned short*)alloc(64 * 128 * 2);
    unsigned short* hbuf = (unsigned short*)alloc((size_t)N * 128 * 2);
    float* xcur    = (float*)alloc((size_t)N * 128 * 4);

    hipMemsetAsync(ws, 0, zero_bytes, stream);
    k_wprep<<<64, 256, 0, stream>>>(W2, 128, wt2);
    k_wprep<<<32, 256, 0, stream>>>(W3, 64, wt3);
    k_count<<<(E + 255) / 256, 256, 0, stream>>>(ei, E0, N, counts);
    k_scan_part<<<P, 256, 0, stream>>>(counts, N, part);
    k_scan_top<<<1, 256, 0, stream>>>(part, P, N, row_ptr);
    k_scan_write<<<P, 256, 0, stream>>>(counts, part, N, row_ptr);
    k_scatter<<<(E + 255) / 256, 256, 0, stream>>>(ei, E0, N, row_ptr, cursor, csr);
    k_graph_ptr<<<(N + 255) / 256, 256, 0, stream>>>(bat, N, G, gp);

    // layer 1: 5 -> 128 (4 heads)
    k_gemm1<<<2048, 256, 0, stream>>>(x, W1, a1s, a1d, hbuf, as_buf, ad_buf, N);
    k_agg<128, 4, 0><<<N, 64, 0, stream>>>(hbuf, as_buf, ad_buf, row_ptr, csr, b1, xcur, N);
    k_bn_stats<<<256, 1024, 0, stream>>>(xcur, N, sums1, sumsq1, tick1, g1, be1, 1.f / N, coefs, coefb);

    // layer 2: 128 -> 128 (4 heads), MFMA, BN1+ELU fused into X staging
    k_gemm_mfma<128, 4, true><<<(N + 63) / 64, 256, 0, stream>>>(
        xcur, wt2, a2s, a2d, coefs, coefb, hbuf, as_buf, ad_buf, N);
    k_agg<128, 4, 0><<<N, 64, 0, stream>>>(hbuf, as_buf, ad_buf, row_ptr, csr, b2, xcur, N);
    k_bn_stats<<<256, 1024, 0, stream>>>(xcur, N, sums2, sumsq2, tick2, g2, be2, 1.f / N, coefs, coefb);

    // layer 3: 128 -> 64 (1 head), MFMA, BN2+ELU fused into X staging, ELU in agg
    k_gemm_mfma<64, 1, true><<<(N + 63) / 64, 256, 0, stream>>>(
        xcur, wt3, a3s, a3d, coefs, coefb, hbuf, as_buf, ad_buf, N);
    k_agg<64, 1, 1><<<N, 64, 0, stream>>>(hbuf, as_buf, ad_buf, row_ptr, csr, b3, xcur, N);

    // pooling
    {
        dim3 grid(16, G);
        k_pool_part<<<grid, 256, 0, stream>>>(xcur, gp, psum, pmax);
        k_pool_fin<<<G, 64, 0, stream>>>(psum, pmax, gp, out);
    }
}

// Round 9
// 284.099 us; speedup vs baseline: 1.3846x; 1.3846x over previous
//
#include <hip/hip_runtime.h>
#include <math.h>

#define NEG_SLOPE 0.2f
#define BN_EPS 1e-5f

typedef __attribute__((ext_vector_type(8))) short short8;     // 8 bf16 (4 VGPRs)
typedef __attribute__((ext_vector_type(4))) float f32x4;

__device__ __forceinline__ float lrelu_f(float x){ return x > 0.f ? x : NEG_SLOPE * x; }
__device__ __forceinline__ float elu_f(float x){ return x > 0.f ? x : __expf(x) - 1.f; }

// float -> bf16 (round-to-nearest-even), and unpack helpers
__device__ __forceinline__ unsigned short f2bf(float f){
    unsigned u = __float_as_uint(f);
    return (unsigned short)((u + 0x7fffu + ((u >> 16) & 1u)) >> 16);
}
__device__ __forceinline__ float bf_lo(unsigned v){ return __uint_as_float(v << 16); }
__device__ __forceinline__ float bf_hi(unsigned v){ return __uint_as_float(v & 0xffff0000u); }
__device__ __forceinline__ float bf2f(unsigned short b){ return __uint_as_float((unsigned)b << 16); }

// ordered-uint encoding for float atomicMax
__device__ __forceinline__ unsigned enc_f(float x){
    unsigned b = __float_as_uint(x);
    return (b & 0x80000000u) ? ~b : (b | 0x80000000u);
}
__device__ __forceinline__ float dec_f(unsigned u){
    return __uint_as_float((u & 0x80000000u) ? (u & 0x7FFFFFFFu) : ~u);
}

// ---------- CSR build ----------
__global__ void k_count(const int* __restrict__ ei, int E0, int N, int* __restrict__ counts){
    int i = blockIdx.x * blockDim.x + threadIdx.x;
    int tot = E0 + N;
    if (i >= tot) return;
    int dst = (i < E0) ? ei[E0 + i] : (i - E0);
    atomicAdd(&counts[dst], 1);
}

__global__ void k_scan_part(const int* __restrict__ counts, int n, int* __restrict__ part){
    __shared__ int sh[256];
    int tid = threadIdx.x;
    int i = blockIdx.x * 256 + tid;
    int v = (i < n) ? counts[i] : 0;
    sh[tid] = v;
    __syncthreads();
    for (int o = 128; o > 0; o >>= 1){
        if (tid < o) sh[tid] += sh[tid + o];
        __syncthreads();
    }
    if (tid == 0) part[blockIdx.x] = sh[0];
}

__global__ void k_scan_top(int* __restrict__ part, int P, int n, int* __restrict__ row_ptr){
    __shared__ int sh[256];
    int tid = threadIdx.x;
    int v = (tid < P) ? part[tid] : 0;
    sh[tid] = v;
    __syncthreads();
    for (int o = 1; o < 256; o <<= 1){
        int t = (tid >= o) ? sh[tid - o] : 0;
        __syncthreads();
        sh[tid] += t;
        __syncthreads();
    }
    if (tid < P) part[tid] = sh[tid] - v;
    if (tid == 0) row_ptr[n] = sh[255];
}

__global__ void k_scan_write(const int* __restrict__ counts, const int* __restrict__ part,
                             int n, int* __restrict__ row_ptr){
    __shared__ int sh[256];
    int tid = threadIdx.x;
    int i = blockIdx.x * 256 + tid;
    int v = (i < n) ? counts[i] : 0;
    sh[tid] = v;
    __syncthreads();
    for (int o = 1; o < 256; o <<= 1){
        int t = (tid >= o) ? sh[tid - o] : 0;
        __syncthreads();
        sh[tid] += t;
        __syncthreads();
    }
    if (i < n) row_ptr[i] = part[blockIdx.x] + sh[tid] - v;
}

__global__ void k_scatter(const int* __restrict__ ei, int E0, int N,
                          const int* __restrict__ row_ptr, int* __restrict__ cursor,
                          int* __restrict__ csr_src){
    int i = blockIdx.x * blockDim.x + threadIdx.x;
    int tot = E0 + N;
    if (i >= tot) return;
    int src, dst;
    if (i < E0){ src = ei[i]; dst = ei[E0 + i]; } else { src = dst = i - E0; }
    int pos = atomicAdd(&cursor[dst], 1);
    csr_src[row_ptr[dst] + pos] = src;
}

__global__ void k_graph_ptr(const int* __restrict__ batch, int N, int G, int* __restrict__ gp){
    int i = blockIdx.x * blockDim.x + threadIdx.x;
    if (i >= N) return;
    int b = batch[i];
    if (i == 0){ for (int g = 0; g <= b; ++g) gp[g] = 0; }
    else { int pb = batch[i - 1]; for (int g = pb + 1; g <= b; ++g) gp[g] = i; }
    if (i == N - 1){ for (int g = b + 1; g <= G; ++g) gp[g] = N; }
}

// ---------- W prep: fp32 [128][OUT] -> bf16 transposed [OUT][128] ----------
__global__ void k_wprep(const float* __restrict__ W, int OUT, unsigned short* __restrict__ Wt){
    int i = blockIdx.x * 256 + threadIdx.x;
    if (i >= 128 * OUT) return;
    int k = i / OUT, c = i % OUT;
    Wt[c * 128 + k] = f2bf(W[i]);
}

// ---------- layer 1 GEMM (IN=5 -> OUT=128, H=4) + attention dots; h stored bf16 ----------
__global__ void k_gemm1(const float* __restrict__ X, const float* __restrict__ W,
                        const float* __restrict__ atts, const float* __restrict__ attd,
                        unsigned short* __restrict__ h, float* __restrict__ as_,
                        float* __restrict__ ad_, int N){
    __shared__ float Wl[5 * 128];
    int tid = threadIdx.x;
    for (int i = tid; i < 5 * 128; i += 256) Wl[i] = W[i];
    __syncthreads();
    int c = tid & 127, local = tid >> 7;
    float as_c = atts[c], ad_c = attd[c];
    for (long node = (long)blockIdx.x * 2 + local; node < N; node += (long)gridDim.x * 2){
        float x0 = X[node * 5 + 0], x1 = X[node * 5 + 1], x2 = X[node * 5 + 2],
              x3 = X[node * 5 + 3], x4 = X[node * 5 + 4];
        float acc = x0 * Wl[c] + x1 * Wl[128 + c] + x2 * Wl[256 + c] +
                    x3 * Wl[384 + c] + x4 * Wl[512 + c];
        float vs = acc * as_c, vd = acc * ad_c;
#pragma unroll
        for (int m = 1; m < 32; m <<= 1){ vs += __shfl_xor(vs, m); vd += __shfl_xor(vd, m); }
        h[node * 128 + c] = f2bf(acc);
        if ((c & 31) == 0){ as_[node * 4 + (c >> 5)] = vs; ad_[node * 4 + (c >> 5)] = vd; }
    }
}

// ---------- MFMA GEMM (IN=128 -> OUT, H heads), fused BN+ELU on X, bf16 in, fp32 acc ----------
template<int OUT, int H, bool BN>
__launch_bounds__(256)
__global__ void k_gemm_mfma(const float* __restrict__ X, const unsigned short* __restrict__ Wt,
                            const float* __restrict__ atts, const float* __restrict__ attd,
                            const float* __restrict__ coefs, const float* __restrict__ coefb,
                            unsigned short* __restrict__ h, float* __restrict__ as_,
                            float* __restrict__ ad_, int N){
    constexpr int TM  = 64;
    constexpr int NCT = OUT / 16;
    constexpr int CPH = NCT / H;
    __shared__ unsigned short Xl[TM * 128];
    __shared__ unsigned short Wl[OUT * 128];
    int tid = threadIdx.x;
    long base = (long)blockIdx.x * TM;

    for (int i = tid; i < OUT * 16; i += 256){
        int r = i >> 4, g = i & 15;
        uint4 v = *(const uint4*)&Wt[r * 128 + g * 8];
        int gs = g ^ (r & 7);
        *(uint4*)&Wl[r * 128 + gs * 8] = v;
    }
    for (int i = tid; i < TM * 16; i += 256){
        int r = i >> 4, g = i & 15;
        long node = base + r;
        uint4 o;
        if (node < N){
            const float* xp = &X[node * 128 + g * 8];
            float f[8];
            *(float4*)&f[0] = *(const float4*)xp;
            *(float4*)&f[4] = *(const float4*)(xp + 4);
#pragma unroll
            for (int j = 0; j < 8; ++j){
                float v = f[j];
                if (BN) v = elu_f(fmaf(v, coefs[g * 8 + j], coefb[g * 8 + j]));
                f[j] = v;
            }
            o.x = (unsigned)f2bf(f[0]) | ((unsigned)f2bf(f[1]) << 16);
            o.y = (unsigned)f2bf(f[2]) | ((unsigned)f2bf(f[3]) << 16);
            o.z = (unsigned)f2bf(f[4]) | ((unsigned)f2bf(f[5]) << 16);
            o.w = (unsigned)f2bf(f[6]) | ((unsigned)f2bf(f[7]) << 16);
        } else {
            o.x = o.y = o.z = o.w = 0u;
        }
        int gs = g ^ (r & 7);
        *(uint4*)&Xl[r * 128 + gs * 8] = o;
    }
    __syncthreads();

    int wid = tid >> 6;
    int lane = tid & 63;
    int lr = lane & 15, lk = lane >> 4;

    short8 afrag[4];
    int arow = wid * 16 + lr;
#pragma unroll
    for (int ks = 0; ks < 4; ++ks){
        int g = ks * 4 + lk;
        int gs = g ^ (arow & 7);
        afrag[ks] = *(const short8*)&Xl[arow * 128 + gs * 8];
    }
    f32x4 acc[NCT];
#pragma unroll
    for (int ct = 0; ct < NCT; ++ct) acc[ct] = (f32x4){0.f, 0.f, 0.f, 0.f};
#pragma unroll
    for (int ct = 0; ct < NCT; ++ct){
        int brow = ct * 16 + lr;
#pragma unroll
        for (int ks = 0; ks < 4; ++ks){
            int g = ks * 4 + lk;
            int gs = g ^ (brow & 7);
            short8 bfrag = *(const short8*)&Wl[brow * 128 + gs * 8];
            acc[ct] = __builtin_amdgcn_mfma_f32_16x16x32_bf16(afrag[ks], bfrag, acc[ct], 0, 0, 0);
        }
    }
    float ps[H][4], pd[H][4];
#pragma unroll
    for (int hh = 0; hh < H; ++hh)
#pragma unroll
        for (int j = 0; j < 4; ++j){ ps[hh][j] = 0.f; pd[hh][j] = 0.f; }
#pragma unroll
    for (int ct = 0; ct < NCT; ++ct){
        int col = ct * 16 + lr;
        int hh = ct / CPH;
        float asv = atts[col], adv = attd[col];
#pragma unroll
        for (int j = 0; j < 4; ++j){
            float v = acc[ct][j];
            long node = base + wid * 16 + lk * 4 + j;
            if (node < N) h[node * OUT + col] = f2bf(v);
            ps[hh][j] += v * asv;
            pd[hh][j] += v * adv;
        }
    }
#pragma unroll
    for (int m = 1; m < 16; m <<= 1){
#pragma unroll
        for (int hh = 0; hh < H; ++hh)
#pragma unroll
            for (int j = 0; j < 4; ++j){
                ps[hh][j] += __shfl_xor(ps[hh][j], m);
                pd[hh][j] += __shfl_xor(pd[hh][j], m);
            }
    }
    if (lr == 0){
#pragma unroll
        for (int j = 0; j < 4; ++j){
            long node = base + wid * 16 + lk * 4 + j;
            if (node < N){
#pragma unroll
                for (int hh = 0; hh < H; ++hh){
                    as_[node * H + hh] = ps[hh][j];
                    ad_[node * H + hh] = pd[hh][j];
                }
            }
        }
    }
}

// ---------- GAT aggregation ----------
template<int C, int H, int ACT>
__global__ void k_agg(const unsigned short* __restrict__ h, const float* __restrict__ as_,
                      const float* __restrict__ ad_, const int* __restrict__ row_ptr,
                      const int* __restrict__ csr_src, const float* __restrict__ bias,
                      float* __restrict__ out, int N){
    constexpr int CPL = C / 64;
    constexpr int GROUP = C / H;
    int n = blockIdx.x;
    if (n >= N) return;
    int lane = threadIdx.x;
    int hh = (CPL * lane) / GROUP;
    float ad = ad_[n * H + hh];
    int beg = row_ptr[n], end = row_ptr[n + 1];
    float accx = 0.f, accy = 0.f, dn = 0.f;
    const unsigned* h32 = (const unsigned*)h;
    int e = beg;
    for (; e + 2 <= end; e += 2){
        int s0 = csr_src[e], s1 = csr_src[e + 1];
        float a0 = as_[s0 * H + hh], a1 = as_[s1 * H + hh];
        unsigned v0, v1; unsigned short w0, w1;
        if (CPL == 2){ v0 = h32[(long)s0 * 64 + lane]; v1 = h32[(long)s1 * 64 + lane]; }
        else { w0 = h[(long)s0 * 64 + lane]; w1 = h[(long)s1 * 64 + lane]; }
        float p0 = __expf(lrelu_f(a0 + ad));
        float p1 = __expf(lrelu_f(a1 + ad));
        dn += p0 + p1;
        if (CPL == 2){
            accx += p0 * bf_lo(v0) + p1 * bf_lo(v1);
            accy += p0 * bf_hi(v0) + p1 * bf_hi(v1);
        } else {
            accx += p0 * bf2f(w0) + p1 * bf2f(w1);
        }
    }
    if (e < end){
        int s0 = csr_src[e];
        float p0 = __expf(lrelu_f(as_[s0 * H + hh] + ad));
        dn += p0;
        if (CPL == 2){
            unsigned v0 = h32[(long)s0 * 64 + lane];
            accx += p0 * bf_lo(v0); accy += p0 * bf_hi(v0);
        } else {
            accx += p0 * bf2f(h[(long)s0 * 64 + lane]);
        }
    }
    float inv = 1.f / dn;
    if (CPL == 2){
        float vx = accx * inv + bias[2 * lane];
        float vy = accy * inv + bias[2 * lane + 1];
        if (ACT == 1){ vx = elu_f(vx); vy = elu_f(vy); }
        float2 o; o.x = vx; o.y = vy;
        *(float2*)&out[(long)n * C + 2 * lane] = o;
    } else {
        float v = accx * inv + bias[lane];
        if (ACT == 1) v = elu_f(v);
        out[(long)n * C + lane] = v;
    }
}

// ---------- BN stats v3: no atomics. Stage 1: per-block partials (4x unrolled MLP). ----------
__launch_bounds__(256)
__global__ void k_bn_part(const float* __restrict__ x, int N,
                          float* __restrict__ ps, float* __restrict__ pq){
    __shared__ float4 lsum[256], lsq[256];
    int tid = threadIdx.x;
    int cq = tid & 31;           // channel quad: channels cq*4..cq*4+3
    int rg = tid >> 5;           // row group 0..7
    int rpb = (N + gridDim.x - 1) / gridDim.x;
    int lo = blockIdx.x * rpb;
    int hi = lo + rpb; if (hi > N) hi = N;
    float4 s = {0.f, 0.f, 0.f, 0.f}, q = {0.f, 0.f, 0.f, 0.f};
    int r = lo + rg;
    // 4x unrolled: 4 independent float4 loads in flight per thread
    for (; r + 24 < hi; r += 32){
        float4 v0 = *(const float4*)&x[(long)r * 128 + cq * 4];
        float4 v1 = *(const float4*)&x[(long)(r + 8) * 128 + cq * 4];
        float4 v2 = *(const float4*)&x[(long)(r + 16) * 128 + cq * 4];
        float4 v3 = *(const float4*)&x[(long)(r + 24) * 128 + cq * 4];
        s.x += v0.x + v1.x + v2.x + v3.x;
        s.y += v0.y + v1.y + v2.y + v3.y;
        s.z += v0.z + v1.z + v2.z + v3.z;
        s.w += v0.w + v1.w + v2.w + v3.w;
        q.x += v0.x * v0.x + v1.x * v1.x + v2.x * v2.x + v3.x * v3.x;
        q.y += v0.y * v0.y + v1.y * v1.y + v2.y * v2.y + v3.y * v3.y;
        q.z += v0.z * v0.z + v1.z * v1.z + v2.z * v2.z + v3.z * v3.z;
        q.w += v0.w * v0.w + v1.w * v1.w + v2.w * v2.w + v3.w * v3.w;
    }
    for (; r < hi; r += 8){
        float4 v = *(const float4*)&x[(long)r * 128 + cq * 4];
        s.x += v.x; s.y += v.y; s.z += v.z; s.w += v.w;
        q.x += v.x * v.x; q.y += v.y * v.y; q.z += v.z * v.z; q.w += v.w * v.w;
    }
    lsum[tid] = s; lsq[tid] = q;
    __syncthreads();
    for (int o = 4; o > 0; o >>= 1){
        if (rg < o){
            float4 s2 = lsum[tid + o * 32], q2 = lsq[tid + o * 32];
            s.x += s2.x; s.y += s2.y; s.z += s2.z; s.w += s2.w;
            q.x += q2.x; q.y += q2.y; q.z += q2.z; q.w += q2.w;
            lsum[tid] = s; lsq[tid] = q;
        }
        __syncthreads();
    }
    if (rg == 0){
        *(float4*)&ps[(long)blockIdx.x * 128 + cq * 4] = s;
        *(float4*)&pq[(long)blockIdx.x * 128 + cq * 4] = q;
    }
}

// ---------- Stage 2: reduce PB partials per channel, write BN coefs ----------
__launch_bounds__(1024)
__global__ void k_bn_fin(const float* __restrict__ ps, const float* __restrict__ pq, int PB,
                         const float* __restrict__ g, const float* __restrict__ be,
                         float invN, float* __restrict__ cs, float* __restrict__ cb){
    __shared__ float sh_s[1024], sh_q[1024];
    int tid = threadIdx.x;
    int c = tid & 127, sl = tid >> 7;   // 8 slices
    float s = 0.f, q = 0.f;
    for (int b = sl; b < PB; b += 8){
        s += ps[(long)b * 128 + c];
        q += pq[(long)b * 128 + c];
    }
    sh_s[tid] = s; sh_q[tid] = q;
    __syncthreads();
    for (int o = 4; o > 0; o >>= 1){
        if (sl < o){
            s += sh_s[tid + o * 128]; q += sh_q[tid + o * 128];
            sh_s[tid] = s; sh_q[tid] = q;
        }
        __syncthreads();
    }
    if (sl == 0){
        float mu = s * invN;
        float var = q * invN - mu * mu;
        float sc = g[c] * rsqrtf(var + BN_EPS);
        cs[c] = sc;
        cb[c] = be[c] - mu * sc;
    }
}

// ---------- pooling ----------
__global__ void k_pool_part(const float* __restrict__ x, const int* __restrict__ gp,
                            float* __restrict__ psum, unsigned* __restrict__ pmax){
    constexpr int S = 16;
    __shared__ float ssum[256], smax[256];
    int g = blockIdx.y;
    int split = blockIdx.x;
    int tid = threadIdx.x;
    int c = tid & 63, sub = tid >> 6;
    int beg = gp[g], end = gp[g + 1];
    int len = end - beg;
    int chunk = (len + S - 1) / S;
    int lo = beg + split * chunk;
    int hi = lo + chunk; if (hi > end) hi = end;
    if (lo >= hi) return;
    float s = 0.f, mx = -1e30f;
    for (int i = lo + sub; i < hi; i += 4){
        float v = x[(long)i * 64 + c];
        s += v; mx = fmaxf(mx, v);
    }
    ssum[tid] = s; smax[tid] = mx;
    __syncthreads();
    if (tid < 64){
        for (int k = 1; k < 4; ++k){ s += ssum[tid + 64 * k]; mx = fmaxf(mx, smax[tid + 64 * k]); }
        atomicAdd(&psum[g * 64 + c], s);
        atomicMax(&pmax[g * 64 + c], enc_f(mx));
    }
}

__global__ void k_pool_fin(const float* __restrict__ psum, const unsigned* __restrict__ pmax,
                           const int* __restrict__ gp, float* __restrict__ out){
    int g = blockIdx.x;
    int c = threadIdx.x;
    int cnt = gp[g + 1] - gp[g];
    float mean = (cnt > 0) ? psum[g * 64 + c] / (float)cnt : 0.f;
    float mx   = (cnt > 0) ? dec_f(pmax[g * 64 + c]) : 0.f;
    out[g * 128 + c]      = mean;
    out[g * 128 + 64 + c] = mx;
}

extern "C" void kernel_launch(void* const* d_in, const int* in_sizes, int n_in,
                              void* d_out, int out_size, void* d_ws, size_t ws_size,
                              hipStream_t stream){
    const float* x   = (const float*)d_in[0];
    const int*   ei  = (const int*)d_in[1];
    const int*   bat = (const int*)d_in[2];
    const float* W1  = (const float*)d_in[3];
    const float* a1s = (const float*)d_in[4];
    const float* a1d = (const float*)d_in[5];
    const float* b1  = (const float*)d_in[6];
    const float* g1  = (const float*)d_in[7];
    const float* be1 = (const float*)d_in[8];
    const float* W2  = (const float*)d_in[9];
    const float* a2s = (const float*)d_in[10];
    const float* a2d = (const float*)d_in[11];
    const float* b2  = (const float*)d_in[12];
    const float* g2  = (const float*)d_in[13];
    const float* be2 = (const float*)d_in[14];
    const float* W3  = (const float*)d_in[15];
    const float* a3s = (const float*)d_in[16];
    const float* a3d = (const float*)d_in[17];
    const float* b3  = (const float*)d_in[18];
    float* out = (float*)d_out;

    int N  = in_sizes[2];        // 50000
    int E0 = in_sizes[1] / 2;    // 600000
    int E  = E0 + N;
    const int G = 64;
    int P  = (N + 255) / 256;
    const int PB = 512;          // bn partial blocks

    char* ws = (char*)d_ws;
    size_t off = 0;
    auto alloc = [&](size_t bytes) -> char* {
        char* p = ws + off;
        off += (bytes + 255) & ~(size_t)255;
        return p;
    };
    // --- zero-init region ---
    int*      counts  = (int*)alloc((size_t)N * 4);
    int*      cursor  = (int*)alloc((size_t)N * 4);
    float*    psum    = (float*)alloc((size_t)G * 64 * 4);
    unsigned* pmax    = (unsigned*)alloc((size_t)G * 64 * 4);
    size_t zero_bytes = off;
    // --- rest ---
    int*   part    = (int*)alloc(256 * 4);
    int*   row_ptr = (int*)alloc((size_t)(N + 1) * 4);
    int*   csr     = (int*)alloc((size_t)E * 4);
    int*   gp      = (int*)alloc((size_t)(G + 1) * 4);
    float* as_buf  = (float*)alloc((size_t)N * 4 * 4);
    float* ad_buf  = (float*)alloc((size_t)N * 4 * 4);
    float* coefs   = (float*)alloc(128 * 4);
    float* coefb   = (float*)alloc(128 * 4);
    float* bn_ps   = (float*)alloc((size_t)PB * 128 * 4);
    float* bn_pq   = (float*)alloc((size_t)PB * 128 * 4);
    unsigned short* wt2 = (unsigned short*)alloc(128 * 128 * 2);
    unsigned short* wt3 = (unsigned short*)alloc(64 * 128 * 2);
    unsigned short* hbuf = (unsigned short*)alloc((size_t)N * 128 * 2);
    float* xcur    = (float*)alloc((size_t)N * 128 * 4);

    hipMemsetAsync(ws, 0, zero_bytes, stream);
    k_wprep<<<64, 256, 0, stream>>>(W2, 128, wt2);
    k_wprep<<<32, 256, 0, stream>>>(W3, 64, wt3);
    k_count<<<(E + 255) / 256, 256, 0, stream>>>(ei, E0, N, counts);
    k_scan_part<<<P, 256, 0, stream>>>(counts, N, part);
    k_scan_top<<<1, 256, 0, stream>>>(part, P, N, row_ptr);
    k_scan_write<<<P, 256, 0, stream>>>(counts, part, N, row_ptr);
    k_scatter<<<(E + 255) / 256, 256, 0, stream>>>(ei, E0, N, row_ptr, cursor, csr);
    k_graph_ptr<<<(N + 255) / 256, 256, 0, stream>>>(bat, N, G, gp);

    // layer 1: 5 -> 128 (4 heads)
    k_gemm1<<<2048, 256, 0, stream>>>(x, W1, a1s, a1d, hbuf, as_buf, ad_buf, N);
    k_agg<128, 4, 0><<<N, 64, 0, stream>>>(hbuf, as_buf, ad_buf, row_ptr, csr, b1, xcur, N);
    k_bn_part<<<PB, 256, 0, stream>>>(xcur, N, bn_ps, bn_pq);
    k_bn_fin<<<1, 1024, 0, stream>>>(bn_ps, bn_pq, PB, g1, be1, 1.f / N, coefs, coefb);

    // layer 2: 128 -> 128 (4 heads), MFMA, BN1+ELU fused into X staging
    k_gemm_mfma<128, 4, true><<<(N + 63) / 64, 256, 0, stream>>>(
        xcur, wt2, a2s, a2d, coefs, coefb, hbuf, as_buf, ad_buf, N);
    k_agg<128, 4, 0><<<N, 64, 0, stream>>>(hbuf, as_buf, ad_buf, row_ptr, csr, b2, xcur, N);
    k_bn_part<<<PB, 256, 0, stream>>>(xcur, N, bn_ps, bn_pq);
    k_bn_fin<<<1, 1024, 0, stream>>>(bn_ps, bn_pq, PB, g2, be2, 1.f / N, coefs, coefb);

    // layer 3: 128 -> 64 (1 head), MFMA, BN2+ELU fused into X staging, ELU in agg
    k_gemm_mfma<64, 1, true><<<(N + 63) / 64, 256, 0, stream>>>(
        xcur, wt3, a3s, a3d, coefs, coefb, hbuf, as_buf, ad_buf, N);
    k_agg<64, 1, 1><<<N, 64, 0, stream>>>(hbuf, as_buf, ad_buf, row_ptr, csr, b3, xcur, N);

    // pooling
    {
        dim3 grid(16, G);
        k_pool_part<<<grid, 256, 0, stream>>>(xcur, gp, psum, pmax);
        k_pool_fin<<<G, 64, 0, stream>>>(psum, pmax, gp, out);
    }
}

// Round 10
// 284.092 us; speedup vs baseline: 1.3846x; 1.0000x over previous
//
#include <hip/hip_runtime.h>
#include <math.h>

#define NEG_SLOPE 0.2f
#define BN_EPS 1e-5f

typedef __attribute__((ext_vector_type(8))) short short8;     // 8 bf16 (4 VGPRs)
typedef __attribute__((ext_vector_type(4))) float f32x4;

__device__ __forceinline__ float lrelu_f(float x){ return x > 0.f ? x : NEG_SLOPE * x; }
__device__ __forceinline__ float elu_f(float x){ return x > 0.f ? x : __expf(x) - 1.f; }

__device__ __forceinline__ unsigned short f2bf(float f){
    unsigned u = __float_as_uint(f);
    return (unsigned short)((u + 0x7fffu + ((u >> 16) & 1u)) >> 16);
}
__device__ __forceinline__ float bf_lo(unsigned v){ return __uint_as_float(v << 16); }
__device__ __forceinline__ float bf_hi(unsigned v){ return __uint_as_float(v & 0xffff0000u); }
__device__ __forceinline__ float bf2f(unsigned short b){ return __uint_as_float((unsigned)b << 16); }

__device__ __forceinline__ unsigned enc_f(float x){
    unsigned b = __float_as_uint(x);
    return (b & 0x80000000u) ? ~b : (b | 0x80000000u);
}
__device__ __forceinline__ float dec_f(unsigned u){
    return __uint_as_float((u & 0x80000000u) ? (u & 0x7FFFFFFFu) : ~u);
}

// ---------- fused prep: edge-count + graph_ptr + W2/W3 bf16-transpose + u-vectors ----------
__global__ void k_prep(const int* __restrict__ ei, int E0, int N, int Bc, int Bg,
                       const int* __restrict__ batch, int G,
                       int* __restrict__ counts, int* __restrict__ gp,
                       const float* __restrict__ W1, const float* __restrict__ a1s,
                       const float* __restrict__ a1d,
                       const float* __restrict__ W2, const float* __restrict__ W3,
                       unsigned short* __restrict__ wt2, unsigned short* __restrict__ wt3,
                       float* __restrict__ u_s, float* __restrict__ u_d){
    int b = blockIdx.x, tid = threadIdx.x;
    if (b < Bc){
        int i = b * 256 + tid, tot = E0 + N;
        if (i < tot){
            int dst = (i < E0) ? ei[E0 + i] : (i - E0);
            atomicAdd(&counts[dst], 1);
        }
    } else if (b < Bc + Bg){
        int i = (b - Bc) * 256 + tid;
        if (i < N){
            int bb = batch[i];
            if (i == 0){ for (int g = 0; g <= bb; ++g) gp[g] = 0; }
            else { int pb = batch[i - 1]; for (int g = pb + 1; g <= bb; ++g) gp[g] = i; }
            if (i == N - 1){ for (int g = bb + 1; g <= G; ++g) gp[g] = N; }
        }
    } else if (b < Bc + Bg + 96){
        int i = (b - Bc - Bg) * 256 + tid;   // 0..24575
        if (i < 128 * 128){
            int k = i / 128, c = i % 128;
            wt2[c * 128 + k] = f2bf(W2[i]);
        } else if (i < 128 * 128 + 128 * 64){
            int j = i - 128 * 128;
            int k = j / 64, c = j % 64;
            wt3[c * 128 + k] = f2bf(W3[j]);
        }
    } else {
        // u_s[k*4+hh] = sum_j W1[k][hh*32+j] * a1s[hh][j]  (and u_d with a1d)
        if (tid < 40){
            int t2 = tid % 20;
            int k = t2 / 4, hh = t2 % 4;
            const float* att = (tid < 20) ? a1s : a1d;
            float s = 0.f;
            for (int j = 0; j < 32; ++j) s += W1[k * 128 + hh * 32 + j] * att[hh * 32 + j];
            if (tid < 20) u_s[k * 4 + hh] = s; else u_d[k * 4 + hh] = s;
        }
    }
}

// ---------- scan: per-block sums, then write (each block computes its own prefix of parts) ----------
__global__ void k_scan_part(const int* __restrict__ counts, int n, int* __restrict__ part){
    __shared__ int sh[256];
    int tid = threadIdx.x;
    int i = blockIdx.x * 256 + tid;
    int v = (i < n) ? counts[i] : 0;
    sh[tid] = v;
    __syncthreads();
    for (int o = 128; o > 0; o >>= 1){
        if (tid < o) sh[tid] += sh[tid + o];
        __syncthreads();
    }
    if (tid == 0) part[blockIdx.x] = sh[0];
}

__global__ void k_scan_write(const int* __restrict__ counts, const int* __restrict__ part,
                             int n, int* __restrict__ row_ptr){
    __shared__ int sh[256], rsh[256];
    __shared__ int offs;
    int tid = threadIdx.x, bid = blockIdx.x;
    // block offset = sum part[0..bid)
    int po = 0;
    for (int j = tid; j < bid; j += 256) po += part[j];
    rsh[tid] = po;
    __syncthreads();
    for (int o = 128; o > 0; o >>= 1){
        if (tid < o) rsh[tid] += rsh[tid + o];
        __syncthreads();
    }
    if (tid == 0) offs = rsh[0];
    __syncthreads();
    int i = bid * 256 + tid;
    int v = (i < n) ? counts[i] : 0;
    sh[tid] = v;
    __syncthreads();
    for (int o = 1; o < 256; o <<= 1){
        int t = (tid >= o) ? sh[tid - o] : 0;
        __syncthreads();
        sh[tid] += t;
        __syncthreads();
    }
    if (i < n) row_ptr[i] = offs + sh[tid] - v;
    if (bid == gridDim.x - 1 && tid == 255) row_ptr[n] = offs + sh[255];
}

__global__ void k_scatter(const int* __restrict__ ei, int E0, int N,
                          const int* __restrict__ row_ptr, int* __restrict__ cursor,
                          int* __restrict__ csr_src){
    int i = blockIdx.x * blockDim.x + threadIdx.x;
    int tot = E0 + N;
    if (i >= tot) return;
    int src, dst;
    if (i < E0){ src = ei[i]; dst = ei[E0 + i]; } else { src = dst = i - E0; }
    int pos = atomicAdd(&cursor[dst], 1);
    csr_src[row_ptr[dst] + pos] = src;
}

// ---------- layer-1 fused GAT: rank-5 recompute, no materialized h ----------
// h1[s,c] = sum_k X[s,k]*W1[k,c]; a_s[s,hh] = sum_k X[s,k]*u_s[k,hh]. Per edge: 20B gather.
__launch_bounds__(512)
__global__ void k_agg1(const float* __restrict__ X, const float* __restrict__ W1,
                       const float* __restrict__ u_s, const float* __restrict__ u_d,
                       const int* __restrict__ row_ptr, const int* __restrict__ csr_src,
                       const float* __restrict__ bias, float* __restrict__ out, int N){
    int wid = threadIdx.x >> 6, lane = threadIdx.x & 63;
    long n = (long)blockIdx.x * 8 + wid;
    if (n >= N) return;
    int hh = lane >> 4;         // head of both channels (c0/32)
    int c0 = lane * 2;
    float2 wv[5]; float us[5], ud[5];
#pragma unroll
    for (int k = 0; k < 5; ++k){
        wv[k] = *(const float2*)&W1[k * 128 + c0];
        us[k] = u_s[k * 4 + hh];
        ud[k] = u_d[k * 4 + hh];
    }
    float xd[5];
#pragma unroll
    for (int k = 0; k < 5; ++k) xd[k] = X[n * 5 + k];
    float ad = xd[0]*ud[0] + xd[1]*ud[1] + xd[2]*ud[2] + xd[3]*ud[3] + xd[4]*ud[4];
    int beg = row_ptr[n], end = row_ptr[n + 1];
    float accx = 0.f, accy = 0.f, dn = 0.f;
    int e = beg;
    for (; e + 2 <= end; e += 2){
        int s0 = csr_src[e], s1 = csr_src[e + 1];
        float a0[5], a1[5];
#pragma unroll
        for (int k = 0; k < 5; ++k){ a0[k] = X[(long)s0 * 5 + k]; a1[k] = X[(long)s1 * 5 + k]; }
        float as0 = a0[0]*us[0] + a0[1]*us[1] + a0[2]*us[2] + a0[3]*us[3] + a0[4]*us[4];
        float as1 = a1[0]*us[0] + a1[1]*us[1] + a1[2]*us[2] + a1[3]*us[3] + a1[4]*us[4];
        float p0 = __expf(lrelu_f(as0 + ad));
        float p1 = __expf(lrelu_f(as1 + ad));
        float hx0 = a0[0]*wv[0].x + a0[1]*wv[1].x + a0[2]*wv[2].x + a0[3]*wv[3].x + a0[4]*wv[4].x;
        float hy0 = a0[0]*wv[0].y + a0[1]*wv[1].y + a0[2]*wv[2].y + a0[3]*wv[3].y + a0[4]*wv[4].y;
        float hx1 = a1[0]*wv[0].x + a1[1]*wv[1].x + a1[2]*wv[2].x + a1[3]*wv[3].x + a1[4]*wv[4].x;
        float hy1 = a1[0]*wv[0].y + a1[1]*wv[1].y + a1[2]*wv[2].y + a1[3]*wv[3].y + a1[4]*wv[4].y;
        dn += p0 + p1;
        accx += p0 * hx0 + p1 * hx1;
        accy += p0 * hy0 + p1 * hy1;
    }
    if (e < end){
        int s0 = csr_src[e];
        float a0[5];
#pragma unroll
        for (int k = 0; k < 5; ++k) a0[k] = X[(long)s0 * 5 + k];
        float as0 = a0[0]*us[0] + a0[1]*us[1] + a0[2]*us[2] + a0[3]*us[3] + a0[4]*us[4];
        float p0 = __expf(lrelu_f(as0 + ad));
        float hx0 = a0[0]*wv[0].x + a0[1]*wv[1].x + a0[2]*wv[2].x + a0[3]*wv[3].x + a0[4]*wv[4].x;
        float hy0 = a0[0]*wv[0].y + a0[1]*wv[1].y + a0[2]*wv[2].y + a0[3]*wv[3].y + a0[4]*wv[4].y;
        dn += p0; accx += p0 * hx0; accy += p0 * hy0;
    }
    float inv = 1.f / dn;
    float2 o; o.x = accx * inv + bias[c0]; o.y = accy * inv + bias[c0 + 1];
    *(float2*)&out[n * 128 + c0] = o;
}

// ---------- MFMA GEMM (IN=128 -> OUT, H heads), fused BN+ELU on X, bf16 in, fp32 acc ----------
template<int OUT, int H, bool BN>
__launch_bounds__(256)
__global__ void k_gemm_mfma(const float* __restrict__ X, const unsigned short* __restrict__ Wt,
                            const float* __restrict__ atts, const float* __restrict__ attd,
                            const float* __restrict__ coefs, const float* __restrict__ coefb,
                            unsigned short* __restrict__ h, float* __restrict__ as_,
                            float* __restrict__ ad_, int N){
    constexpr int TM  = 64;
    constexpr int NCT = OUT / 16;
    constexpr int CPH = NCT / H;
    __shared__ unsigned short Xl[TM * 128];
    __shared__ unsigned short Wl[OUT * 128];
    int tid = threadIdx.x;
    long base = (long)blockIdx.x * TM;

    for (int i = tid; i < OUT * 16; i += 256){
        int r = i >> 4, g = i & 15;
        uint4 v = *(const uint4*)&Wt[r * 128 + g * 8];
        int gs = g ^ (r & 7);
        *(uint4*)&Wl[r * 128 + gs * 8] = v;
    }
    for (int i = tid; i < TM * 16; i += 256){
        int r = i >> 4, g = i & 15;
        long node = base + r;
        uint4 o;
        if (node < N){
            const float* xp = &X[node * 128 + g * 8];
            float f[8];
            *(float4*)&f[0] = *(const float4*)xp;
            *(float4*)&f[4] = *(const float4*)(xp + 4);
#pragma unroll
            for (int j = 0; j < 8; ++j){
                float v = f[j];
                if (BN) v = elu_f(fmaf(v, coefs[g * 8 + j], coefb[g * 8 + j]));
                f[j] = v;
            }
            o.x = (unsigned)f2bf(f[0]) | ((unsigned)f2bf(f[1]) << 16);
            o.y = (unsigned)f2bf(f[2]) | ((unsigned)f2bf(f[3]) << 16);
            o.z = (unsigned)f2bf(f[4]) | ((unsigned)f2bf(f[5]) << 16);
            o.w = (unsigned)f2bf(f[6]) | ((unsigned)f2bf(f[7]) << 16);
        } else {
            o.x = o.y = o.z = o.w = 0u;
        }
        int gs = g ^ (r & 7);
        *(uint4*)&Xl[r * 128 + gs * 8] = o;
    }
    __syncthreads();

    int wid = tid >> 6;
    int lane = tid & 63;
    int lr = lane & 15, lk = lane >> 4;

    short8 afrag[4];
    int arow = wid * 16 + lr;
#pragma unroll
    for (int ks = 0; ks < 4; ++ks){
        int g = ks * 4 + lk;
        int gs = g ^ (arow & 7);
        afrag[ks] = *(const short8*)&Xl[arow * 128 + gs * 8];
    }
    f32x4 acc[NCT];
#pragma unroll
    for (int ct = 0; ct < NCT; ++ct) acc[ct] = (f32x4){0.f, 0.f, 0.f, 0.f};
#pragma unroll
    for (int ct = 0; ct < NCT; ++ct){
        int brow = ct * 16 + lr;
#pragma unroll
        for (int ks = 0; ks < 4; ++ks){
            int g = ks * 4 + lk;
            int gs = g ^ (brow & 7);
            short8 bfrag = *(const short8*)&Wl[brow * 128 + gs * 8];
            acc[ct] = __builtin_amdgcn_mfma_f32_16x16x32_bf16(afrag[ks], bfrag, acc[ct], 0, 0, 0);
        }
    }
    float ps[H][4], pd[H][4];
#pragma unroll
    for (int hh = 0; hh < H; ++hh)
#pragma unroll
        for (int j = 0; j < 4; ++j){ ps[hh][j] = 0.f; pd[hh][j] = 0.f; }
#pragma unroll
    for (int ct = 0; ct < NCT; ++ct){
        int col = ct * 16 + lr;
        int hh = ct / CPH;
        float asv = atts[col], adv = attd[col];
#pragma unroll
        for (int j = 0; j < 4; ++j){
            float v = acc[ct][j];
            long node = base + wid * 16 + lk * 4 + j;
            if (node < N) h[node * OUT + col] = f2bf(v);
            ps[hh][j] += v * asv;
            pd[hh][j] += v * adv;
        }
    }
#pragma unroll
    for (int m = 1; m < 16; m <<= 1){
#pragma unroll
        for (int hh = 0; hh < H; ++hh)
#pragma unroll
            for (int j = 0; j < 4; ++j){
                ps[hh][j] += __shfl_xor(ps[hh][j], m);
                pd[hh][j] += __shfl_xor(pd[hh][j], m);
            }
    }
    if (lr == 0){
#pragma unroll
        for (int j = 0; j < 4; ++j){
            long node = base + wid * 16 + lk * 4 + j;
            if (node < N){
#pragma unroll
                for (int hh = 0; hh < H; ++hh){
                    as_[node * H + hh] = ps[hh][j];
                    ad_[node * H + hh] = pd[hh][j];
                }
            }
        }
    }
}

// ---------- GAT aggregation (layers 2/3): bf16 h gather ----------
template<int C, int H, int ACT>
__global__ void k_agg(const unsigned short* __restrict__ h, const float* __restrict__ as_,
                      const float* __restrict__ ad_, const int* __restrict__ row_ptr,
                      const int* __restrict__ csr_src, const float* __restrict__ bias,
                      float* __restrict__ out, int N){
    constexpr int CPL = C / 64;
    constexpr int GROUP = C / H;
    int n = blockIdx.x;
    if (n >= N) return;
    int lane = threadIdx.x;
    int hh = (CPL * lane) / GROUP;
    float ad = ad_[n * H + hh];
    int beg = row_ptr[n], end = row_ptr[n + 1];
    float accx = 0.f, accy = 0.f, dn = 0.f;
    const unsigned* h32 = (const unsigned*)h;
    int e = beg;
    for (; e + 2 <= end; e += 2){
        int s0 = csr_src[e], s1 = csr_src[e + 1];
        float a0 = as_[s0 * H + hh], a1 = as_[s1 * H + hh];
        unsigned v0, v1; unsigned short w0, w1;
        if (CPL == 2){ v0 = h32[(long)s0 * 64 + lane]; v1 = h32[(long)s1 * 64 + lane]; }
        else { w0 = h[(long)s0 * 64 + lane]; w1 = h[(long)s1 * 64 + lane]; }
        float p0 = __expf(lrelu_f(a0 + ad));
        float p1 = __expf(lrelu_f(a1 + ad));
        dn += p0 + p1;
        if (CPL == 2){
            accx += p0 * bf_lo(v0) + p1 * bf_lo(v1);
            accy += p0 * bf_hi(v0) + p1 * bf_hi(v1);
        } else {
            accx += p0 * bf2f(w0) + p1 * bf2f(w1);
        }
    }
    if (e < end){
        int s0 = csr_src[e];
        float p0 = __expf(lrelu_f(as_[s0 * H + hh] + ad));
        dn += p0;
        if (CPL == 2){
            unsigned v0 = h32[(long)s0 * 64 + lane];
            accx += p0 * bf_lo(v0); accy += p0 * bf_hi(v0);
        } else {
            accx += p0 * bf2f(h[(long)s0 * 64 + lane]);
        }
    }
    float inv = 1.f / dn;
    if (CPL == 2){
        float vx = accx * inv + bias[2 * lane];
        float vy = accy * inv + bias[2 * lane + 1];
        if (ACT == 1){ vx = elu_f(vx); vy = elu_f(vy); }
        float2 o; o.x = vx; o.y = vy;
        *(float2*)&out[(long)n * C + 2 * lane] = o;
    } else {
        float v = accx * inv + bias[lane];
        if (ACT == 1) v = elu_f(v);
        out[(long)n * C + lane] = v;
    }
}

// ---------- BN stats: no atomics, two-pass ----------
__launch_bounds__(256)
__global__ void k_bn_part(const float* __restrict__ x, int N,
                          float* __restrict__ ps, float* __restrict__ pq){
    __shared__ float4 lsum[256], lsq[256];
    int tid = threadIdx.x;
    int cq = tid & 31;
    int rg = tid >> 5;
    int rpb = (N + gridDim.x - 1) / gridDim.x;
    int lo = blockIdx.x * rpb;
    int hi = lo + rpb; if (hi > N) hi = N;
    float4 s = {0.f, 0.f, 0.f, 0.f}, q = {0.f, 0.f, 0.f, 0.f};
    int r = lo + rg;
    for (; r + 24 < hi; r += 32){
        float4 v0 = *(const float4*)&x[(long)r * 128 + cq * 4];
        float4 v1 = *(const float4*)&x[(long)(r + 8) * 128 + cq * 4];
        float4 v2 = *(const float4*)&x[(long)(r + 16) * 128 + cq * 4];
        float4 v3 = *(const float4*)&x[(long)(r + 24) * 128 + cq * 4];
        s.x += v0.x + v1.x + v2.x + v3.x;
        s.y += v0.y + v1.y + v2.y + v3.y;
        s.z += v0.z + v1.z + v2.z + v3.z;
        s.w += v0.w + v1.w + v2.w + v3.w;
        q.x += v0.x * v0.x + v1.x * v1.x + v2.x * v2.x + v3.x * v3.x;
        q.y += v0.y * v0.y + v1.y * v1.y + v2.y * v2.y + v3.y * v3.y;
        q.z += v0.z * v0.z + v1.z * v1.z + v2.z * v2.z + v3.z * v3.z;
        q.w += v0.w * v0.w + v1.w * v1.w + v2.w * v2.w + v3.w * v3.w;
    }
    for (; r < hi; r += 8){
        float4 v = *(const float4*)&x[(long)r * 128 + cq * 4];
        s.x += v.x; s.y += v.y; s.z += v.z; s.w += v.w;
        q.x += v.x * v.x; q.y += v.y * v.y; q.z += v.z * v.z; q.w += v.w * v.w;
    }
    lsum[tid] = s; lsq[tid] = q;
    __syncthreads();
    for (int o = 4; o > 0; o >>= 1){
        if (rg < o){
            float4 s2 = lsum[tid + o * 32], q2 = lsq[tid + o * 32];
            s.x += s2.x; s.y += s2.y; s.z += s2.z; s.w += s2.w;
            q.x += q2.x; q.y += q2.y; q.z += q2.z; q.w += q2.w;
            lsum[tid] = s; lsq[tid] = q;
        }
        __syncthreads();
    }
    if (rg == 0){
        *(float4*)&ps[(long)blockIdx.x * 128 + cq * 4] = s;
        *(float4*)&pq[(long)blockIdx.x * 128 + cq * 4] = q;
    }
}

__launch_bounds__(1024)
__global__ void k_bn_fin(const float* __restrict__ ps, const float* __restrict__ pq, int PB,
                         const float* __restrict__ g, const float* __restrict__ be,
                         float invN, float* __restrict__ cs, float* __restrict__ cb){
    __shared__ float sh_s[1024], sh_q[1024];
    int tid = threadIdx.x;
    int c = tid & 127, sl = tid >> 7;
    float s = 0.f, q = 0.f;
    for (int b = sl; b < PB; b += 8){
        s += ps[(long)b * 128 + c];
        q += pq[(long)b * 128 + c];
    }
    sh_s[tid] = s; sh_q[tid] = q;
    __syncthreads();
    for (int o = 4; o > 0; o >>= 1){
        if (sl < o){
            s += sh_s[tid + o * 128]; q += sh_q[tid + o * 128];
            sh_s[tid] = s; sh_q[tid] = q;
        }
        __syncthreads();
    }
    if (sl == 0){
        float mu = s * invN;
        float var = q * invN - mu * mu;
        float sc = g[c] * rsqrtf(var + BN_EPS);
        cs[c] = sc;
        cb[c] = be[c] - mu * sc;
    }
}

// ---------- pooling ----------
__global__ void k_pool_part(const float* __restrict__ x, const int* __restrict__ gp,
                            float* __restrict__ psum, unsigned* __restrict__ pmax){
    constexpr int S = 16;
    __shared__ float ssum[256], smax[256];
    int g = blockIdx.y;
    int split = blockIdx.x;
    int tid = threadIdx.x;
    int c = tid & 63, sub = tid >> 6;
    int beg = gp[g], end = gp[g + 1];
    int len = end - beg;
    int chunk = (len + S - 1) / S;
    int lo = beg + split * chunk;
    int hi = lo + chunk; if (hi > end) hi = end;
    if (lo >= hi) return;
    float s = 0.f, mx = -1e30f;
    for (int i = lo + sub; i < hi; i += 4){
        float v = x[(long)i * 64 + c];
        s += v; mx = fmaxf(mx, v);
    }
    ssum[tid] = s; smax[tid] = mx;
    __syncthreads();
    if (tid < 64){
        for (int k = 1; k < 4; ++k){ s += ssum[tid + 64 * k]; mx = fmaxf(mx, smax[tid + 64 * k]); }
        atomicAdd(&psum[g * 64 + c], s);
        atomicMax(&pmax[g * 64 + c], enc_f(mx));
    }
}

__global__ void k_pool_fin(const float* __restrict__ psum, const unsigned* __restrict__ pmax,
                           const int* __restrict__ gp, float* __restrict__ out){
    int g = blockIdx.x;
    int c = threadIdx.x;
    int cnt = gp[g + 1] - gp[g];
    float mean = (cnt > 0) ? psum[g * 64 + c] / (float)cnt : 0.f;
    float mx   = (cnt > 0) ? dec_f(pmax[g * 64 + c]) : 0.f;
    out[g * 128 + c]      = mean;
    out[g * 128 + 64 + c] = mx;
}

extern "C" void kernel_launch(void* const* d_in, const int* in_sizes, int n_in,
                              void* d_out, int out_size, void* d_ws, size_t ws_size,
                              hipStream_t stream){
    const float* x   = (const float*)d_in[0];
    const int*   ei  = (const int*)d_in[1];
    const int*   bat = (const int*)d_in[2];
    const float* W1  = (const float*)d_in[3];
    const float* a1s = (const float*)d_in[4];
    const float* a1d = (const float*)d_in[5];
    const float* b1  = (const float*)d_in[6];
    const float* g1  = (const float*)d_in[7];
    const float* be1 = (const float*)d_in[8];
    const float* W2  = (const float*)d_in[9];
    const float* a2s = (const float*)d_in[10];
    const float* a2d = (const float*)d_in[11];
    const float* b2  = (const float*)d_in[12];
    const float* g2  = (const float*)d_in[13];
    const float* be2 = (const float*)d_in[14];
    const float* W3  = (const float*)d_in[15];
    const float* a3s = (const float*)d_in[16];
    const float* a3d = (const float*)d_in[17];
    const float* b3  = (const float*)d_in[18];
    float* out = (float*)d_out;

    int N  = in_sizes[2];        // 50000
    int E0 = in_sizes[1] / 2;    // 600000
    int E  = E0 + N;
    const int G = 64;
    int P  = (N + 255) / 256;    // scan blocks
    const int PB = 512;          // bn partial blocks

    char* ws = (char*)d_ws;
    size_t off = 0;
    auto alloc = [&](size_t bytes) -> char* {
        char* p = ws + off;
        off += (bytes + 255) & ~(size_t)255;
        return p;
    };
    // --- zero-init region ---
    int*      counts  = (int*)alloc((size_t)N * 4);
    int*      cursor  = (int*)alloc((size_t)N * 4);
    float*    psum    = (float*)alloc((size_t)G * 64 * 4);
    unsigned* pmax    = (unsigned*)alloc((size_t)G * 64 * 4);
    size_t zero_bytes = off;
    // --- rest ---
    int*   part    = (int*)alloc(256 * 4);
    int*   row_ptr = (int*)alloc((size_t)(N + 1) * 4);
    int*   csr     = (int*)alloc((size_t)E * 4);
    int*   gp      = (int*)alloc((size_t)(G + 1) * 4);
    float* as_buf  = (float*)alloc((size_t)N * 4 * 4);
    float* ad_buf  = (float*)alloc((size_t)N * 4 * 4);
    float* coefs   = (float*)alloc(128 * 4);
    float* coefb   = (float*)alloc(128 * 4);
    float* u_s     = (float*)alloc(20 * 4);
    float* u_d     = (float*)alloc(20 * 4);
    float* bn_ps   = (float*)alloc((size_t)PB * 128 * 4);
    float* bn_pq   = (float*)alloc((size_t)PB * 128 * 4);
    unsigned short* wt2 = (unsigned short*)alloc(128 * 128 * 2);
    unsigned short* wt3 = (unsigned short*)alloc(64 * 128 * 2);
    unsigned short* hbuf = (unsigned short*)alloc((size_t)N * 128 * 2);
    float* xcur    = (float*)alloc((size_t)N * 128 * 4);

    hipMemsetAsync(ws, 0, zero_bytes, stream);

    // fused prep: count + graph_ptr + W transposes + u vectors
    int Bc = (E + 255) / 256, Bg = (N + 255) / 256;
    k_prep<<<Bc + Bg + 96 + 1, 256, 0, stream>>>(ei, E0, N, Bc, Bg, bat, G, counts, gp,
                                                 W1, a1s, a1d, W2, W3, wt2, wt3, u_s, u_d);
    k_scan_part<<<P, 256, 0, stream>>>(counts, N, part);
    k_scan_write<<<P, 256, 0, stream>>>(counts, part, N, row_ptr);
    k_scatter<<<(E + 255) / 256, 256, 0, stream>>>(ei, E0, N, row_ptr, cursor, csr);

    // layer 1: rank-5 fused GAT (no gemm, no h materialization)
    k_agg1<<<(N + 7) / 8, 512, 0, stream>>>(x, W1, u_s, u_d, row_ptr, csr, b1, xcur, N);
    k_bn_part<<<PB, 256, 0, stream>>>(xcur, N, bn_ps, bn_pq);
    k_bn_fin<<<1, 1024, 0, stream>>>(bn_ps, bn_pq, PB, g1, be1, 1.f / N, coefs, coefb);

    // layer 2: 128 -> 128 (4 heads), MFMA, BN1+ELU fused into X staging
    k_gemm_mfma<128, 4, true><<<(N + 63) / 64, 256, 0, stream>>>(
        xcur, wt2, a2s, a2d, coefs, coefb, hbuf, as_buf, ad_buf, N);
    k_agg<128, 4, 0><<<N, 64, 0, stream>>>(hbuf, as_buf, ad_buf, row_ptr, csr, b2, xcur, N);
    k_bn_part<<<PB, 256, 0, stream>>>(xcur, N, bn_ps, bn_pq);
    k_bn_fin<<<1, 1024, 0, stream>>>(bn_ps, bn_pq, PB, g2, be2, 1.f / N, coefs, coefb);

    // layer 3: 128 -> 64 (1 head), MFMA, BN2+ELU fused into X staging, ELU in agg
    k_gemm_mfma<64, 1, true><<<(N + 63) / 64, 256, 0, stream>>>(
        xcur, wt3, a3s, a3d, coefs, coefb, hbuf, as_buf, ad_buf, N);
    k_agg<64, 1, 1><<<N, 64, 0, stream>>>(hbuf, as_buf, ad_buf, row_ptr, csr, b3, xcur, N);

    // pooling
    {
        dim3 grid(16, G);
        k_pool_part<<<grid, 256, 0, stream>>>(xcur, gp, psum, pmax);
        k_pool_fin<<<G, 64, 0, stream>>>(psum, pmax, gp, out);
    }
}

// Round 11
// 242.455 us; speedup vs baseline: 1.6224x; 1.1717x over previous
//
#include <hip/hip_runtime.h>
#include <math.h>

#define NEG_SLOPE 0.2f
#define BN_EPS 1e-5f

typedef __attribute__((ext_vector_type(8))) short short8;     // 8 bf16 (4 VGPRs)
typedef __attribute__((ext_vector_type(4))) float f32x4;

__device__ __forceinline__ float lrelu_f(float x){ return x > 0.f ? x : NEG_SLOPE * x; }
__device__ __forceinline__ float elu_f(float x){ return x > 0.f ? x : __expf(x) - 1.f; }

__device__ __forceinline__ unsigned short f2bf(float f){
    unsigned u = __float_as_uint(f);
    return (unsigned short)((u + 0x7fffu + ((u >> 16) & 1u)) >> 16);
}
__device__ __forceinline__ float bf_lo(unsigned v){ return __uint_as_float(v << 16); }
__device__ __forceinline__ float bf_hi(unsigned v){ return __uint_as_float(v & 0xffff0000u); }
__device__ __forceinline__ float bf2f(unsigned short b){ return __uint_as_float((unsigned)b << 16); }

__device__ __forceinline__ unsigned enc_f(float x){
    unsigned b = __float_as_uint(x);
    return (b & 0x80000000u) ? ~b : (b | 0x80000000u);
}
__device__ __forceinline__ float dec_f(unsigned u){
    return __uint_as_float((u & 0x80000000u) ? (u & 0x7FFFFFFFu) : ~u);
}

// ---------- fused prep: edge-count + graph_ptr + W2/W3 bf16-transpose + u-vectors ----------
__global__ void k_prep(const int* __restrict__ ei, int E0, int N, int Bc, int Bg,
                       const int* __restrict__ batch, int G,
                       int* __restrict__ counts, int* __restrict__ gp,
                       const float* __restrict__ W1, const float* __restrict__ a1s,
                       const float* __restrict__ a1d,
                       const float* __restrict__ W2, const float* __restrict__ W3,
                       unsigned short* __restrict__ wt2, unsigned short* __restrict__ wt3,
                       float* __restrict__ u_s, float* __restrict__ u_d){
    int b = blockIdx.x, tid = threadIdx.x;
    if (b < Bc){
        int i = b * 256 + tid, tot = E0 + N;
        if (i < tot){
            int dst = (i < E0) ? ei[E0 + i] : (i - E0);
            atomicAdd(&counts[dst], 1);
        }
    } else if (b < Bc + Bg){
        int i = (b - Bc) * 256 + tid;
        if (i < N){
            int bb = batch[i];
            if (i == 0){ for (int g = 0; g <= bb; ++g) gp[g] = 0; }
            else { int pb = batch[i - 1]; for (int g = pb + 1; g <= bb; ++g) gp[g] = i; }
            if (i == N - 1){ for (int g = bb + 1; g <= G; ++g) gp[g] = N; }
        }
    } else if (b < Bc + Bg + 96){
        int i = (b - Bc - Bg) * 256 + tid;   // 0..24575
        if (i < 128 * 128){
            int k = i / 128, c = i % 128;
            wt2[c * 128 + k] = f2bf(W2[i]);
        } else if (i < 128 * 128 + 128 * 64){
            int j = i - 128 * 128;
            int k = j / 64, c = j % 64;
            wt3[c * 128 + k] = f2bf(W3[j]);
        }
    } else {
        // u_s[k*4+hh] = sum_j W1[k][hh*32+j] * a1s[hh][j]  (and u_d with a1d)
        if (tid < 40){
            int t2 = tid % 20;
            int k = t2 / 4, hh = t2 % 4;
            const float* att = (tid < 20) ? a1s : a1d;
            float s = 0.f;
            for (int j = 0; j < 32; ++j) s += W1[k * 128 + hh * 32 + j] * att[hh * 32 + j];
            if (tid < 20) u_s[k * 4 + hh] = s; else u_d[k * 4 + hh] = s;
        }
    }
}

// ---------- scan ----------
__global__ void k_scan_part(const int* __restrict__ counts, int n, int* __restrict__ part){
    __shared__ int sh[256];
    int tid = threadIdx.x;
    int i = blockIdx.x * 256 + tid;
    int v = (i < n) ? counts[i] : 0;
    sh[tid] = v;
    __syncthreads();
    for (int o = 128; o > 0; o >>= 1){
        if (tid < o) sh[tid] += sh[tid + o];
        __syncthreads();
    }
    if (tid == 0) part[blockIdx.x] = sh[0];
}

__global__ void k_scan_write(const int* __restrict__ counts, const int* __restrict__ part,
                             int n, int* __restrict__ row_ptr){
    __shared__ int sh[256], rsh[256];
    __shared__ int offs;
    int tid = threadIdx.x, bid = blockIdx.x;
    int po = 0;
    for (int j = tid; j < bid; j += 256) po += part[j];
    rsh[tid] = po;
    __syncthreads();
    for (int o = 128; o > 0; o >>= 1){
        if (tid < o) rsh[tid] += rsh[tid + o];
        __syncthreads();
    }
    if (tid == 0) offs = rsh[0];
    __syncthreads();
    int i = bid * 256 + tid;
    int v = (i < n) ? counts[i] : 0;
    sh[tid] = v;
    __syncthreads();
    for (int o = 1; o < 256; o <<= 1){
        int t = (tid >= o) ? sh[tid - o] : 0;
        __syncthreads();
        sh[tid] += t;
        __syncthreads();
    }
    if (i < n) row_ptr[i] = offs + sh[tid] - v;
    if (bid == gridDim.x - 1 && tid == 255) row_ptr[n] = offs + sh[255];
}

__global__ void k_scatter(const int* __restrict__ ei, int E0, int N,
                          const int* __restrict__ row_ptr, int* __restrict__ cursor,
                          int* __restrict__ csr_src){
    int i = blockIdx.x * blockDim.x + threadIdx.x;
    int tot = E0 + N;
    if (i >= tot) return;
    int src, dst;
    if (i < E0){ src = ei[i]; dst = ei[E0 + i]; } else { src = dst = i - E0; }
    int pos = atomicAdd(&cursor[dst], 1);
    csr_src[row_ptr[dst] + pos] = src;
}

// ---------- layer-1 fused GAT via rank-5 commutation ----------
// out[n,:] = (y[n,hh,:] @ W1_head + b1) with y[n,hh,k] = sum_e p_e X[s_e,k], p from softmax.
// 16 lanes/node: lane = (hh = ln>>2, sl = ln&3). After sl-reduce, lane's own head matches
// its output channels c = ln*8..ln*8+7 (head = c/32 = ln>>2). No redistribution needed.
__launch_bounds__(256)
__global__ void k_l1(const float* __restrict__ X, const float* __restrict__ W1,
                     const float* __restrict__ u_s, const float* __restrict__ u_d,
                     const int* __restrict__ row_ptr, const int* __restrict__ csr_src,
                     const float* __restrict__ bias, float* __restrict__ out, int N){
    __shared__ float Wl[5 * 128];
    int tid = threadIdx.x;
    for (int i = tid; i < 5 * 128; i += 256) Wl[i] = W1[i];
    __syncthreads();
    int grp = tid >> 4, ln = tid & 15;
    int hh = ln >> 2, sl = ln & 3;
    long n = (long)blockIdx.x * 16 + grp;
    if (n >= N) return;
    float us[5], ud[5];
#pragma unroll
    for (int k = 0; k < 5; ++k){ us[k] = u_s[k * 4 + hh]; ud[k] = u_d[k * 4 + hh]; }
    float ad = 0.f;
#pragma unroll
    for (int k = 0; k < 5; ++k) ad += X[n * 5 + k] * ud[k];
    int beg = row_ptr[n], end = row_ptr[n + 1];
    float y0 = 0.f, y1 = 0.f, y2 = 0.f, y3 = 0.f, y4 = 0.f, dn = 0.f;
    for (int e = beg + sl; e < end; e += 4){
        long s = csr_src[e];
        float x0 = X[s * 5 + 0], x1 = X[s * 5 + 1], x2 = X[s * 5 + 2],
              x3 = X[s * 5 + 3], x4 = X[s * 5 + 4];
        float as = x0 * us[0] + x1 * us[1] + x2 * us[2] + x3 * us[3] + x4 * us[4];
        float p = __expf(lrelu_f(as + ad));
        dn += p;
        y0 += p * x0; y1 += p * x1; y2 += p * x2; y3 += p * x3; y4 += p * x4;
    }
    // reduce over sl (lanes ln^1, ln^2 share head)
#pragma unroll
    for (int m = 1; m < 4; m <<= 1){
        y0 += __shfl_xor(y0, m); y1 += __shfl_xor(y1, m); y2 += __shfl_xor(y2, m);
        y3 += __shfl_xor(y3, m); y4 += __shfl_xor(y4, m); dn += __shfl_xor(dn, m);
    }
    float inv = 1.f / dn;
    y0 *= inv; y1 *= inv; y2 *= inv; y3 *= inv; y4 *= inv;
    int c0 = ln * 8;
    const float4* Wl4 = (const float4*)Wl;
    float4 oa, ob;
    {
        float4 w0a = Wl4[0 * 32 + ln * 2], w0b = Wl4[0 * 32 + ln * 2 + 1];
        float4 w1a = Wl4[1 * 32 + ln * 2], w1b = Wl4[1 * 32 + ln * 2 + 1];
        float4 w2a = Wl4[2 * 32 + ln * 2], w2b = Wl4[2 * 32 + ln * 2 + 1];
        float4 w3a = Wl4[3 * 32 + ln * 2], w3b = Wl4[3 * 32 + ln * 2 + 1];
        float4 w4a = Wl4[4 * 32 + ln * 2], w4b = Wl4[4 * 32 + ln * 2 + 1];
        oa.x = y0*w0a.x + y1*w1a.x + y2*w2a.x + y3*w3a.x + y4*w4a.x + bias[c0 + 0];
        oa.y = y0*w0a.y + y1*w1a.y + y2*w2a.y + y3*w3a.y + y4*w4a.y + bias[c0 + 1];
        oa.z = y0*w0a.z + y1*w1a.z + y2*w2a.z + y3*w3a.z + y4*w4a.z + bias[c0 + 2];
        oa.w = y0*w0a.w + y1*w1a.w + y2*w2a.w + y3*w3a.w + y4*w4a.w + bias[c0 + 3];
        ob.x = y0*w0b.x + y1*w1b.x + y2*w2b.x + y3*w3b.x + y4*w4b.x + bias[c0 + 4];
        ob.y = y0*w0b.y + y1*w1b.y + y2*w2b.y + y3*w3b.y + y4*w4b.y + bias[c0 + 5];
        ob.z = y0*w0b.z + y1*w1b.z + y2*w2b.z + y3*w3b.z + y4*w4b.z + bias[c0 + 6];
        ob.w = y0*w0b.w + y1*w1b.w + y2*w2b.w + y3*w3b.w + y4*w4b.w + bias[c0 + 7];
    }
    *(float4*)&out[n * 128 + c0] = oa;
    *(float4*)&out[n * 128 + c0 + 4] = ob;
}

// ---------- MFMA GEMM (IN=128 -> OUT, H heads), fused BN+ELU on X, bf16 in, fp32 acc ----------
template<int OUT, int H, bool BN>
__launch_bounds__(256)
__global__ void k_gemm_mfma(const float* __restrict__ X, const unsigned short* __restrict__ Wt,
                            const float* __restrict__ atts, const float* __restrict__ attd,
                            const float* __restrict__ coefs, const float* __restrict__ coefb,
                            unsigned short* __restrict__ h, float* __restrict__ as_,
                            float* __restrict__ ad_, int N){
    constexpr int TM  = 64;
    constexpr int NCT = OUT / 16;
    constexpr int CPH = NCT / H;
    __shared__ unsigned short Xl[TM * 128];
    __shared__ unsigned short Wl[OUT * 128];
    int tid = threadIdx.x;
    long base = (long)blockIdx.x * TM;

    for (int i = tid; i < OUT * 16; i += 256){
        int r = i >> 4, g = i & 15;
        uint4 v = *(const uint4*)&Wt[r * 128 + g * 8];
        int gs = g ^ (r & 7);
        *(uint4*)&Wl[r * 128 + gs * 8] = v;
    }
    for (int i = tid; i < TM * 16; i += 256){
        int r = i >> 4, g = i & 15;
        long node = base + r;
        uint4 o;
        if (node < N){
            const float* xp = &X[node * 128 + g * 8];
            float f[8];
            *(float4*)&f[0] = *(const float4*)xp;
            *(float4*)&f[4] = *(const float4*)(xp + 4);
#pragma unroll
            for (int j = 0; j < 8; ++j){
                float v = f[j];
                if (BN) v = elu_f(fmaf(v, coefs[g * 8 + j], coefb[g * 8 + j]));
                f[j] = v;
            }
            o.x = (unsigned)f2bf(f[0]) | ((unsigned)f2bf(f[1]) << 16);
            o.y = (unsigned)f2bf(f[2]) | ((unsigned)f2bf(f[3]) << 16);
            o.z = (unsigned)f2bf(f[4]) | ((unsigned)f2bf(f[5]) << 16);
            o.w = (unsigned)f2bf(f[6]) | ((unsigned)f2bf(f[7]) << 16);
        } else {
            o.x = o.y = o.z = o.w = 0u;
        }
        int gs = g ^ (r & 7);
        *(uint4*)&Xl[r * 128 + gs * 8] = o;
    }
    __syncthreads();

    int wid = tid >> 6;
    int lane = tid & 63;
    int lr = lane & 15, lk = lane >> 4;

    short8 afrag[4];
    int arow = wid * 16 + lr;
#pragma unroll
    for (int ks = 0; ks < 4; ++ks){
        int g = ks * 4 + lk;
        int gs = g ^ (arow & 7);
        afrag[ks] = *(const short8*)&Xl[arow * 128 + gs * 8];
    }
    f32x4 acc[NCT];
#pragma unroll
    for (int ct = 0; ct < NCT; ++ct) acc[ct] = (f32x4){0.f, 0.f, 0.f, 0.f};
#pragma unroll
    for (int ct = 0; ct < NCT; ++ct){
        int brow = ct * 16 + lr;
#pragma unroll
        for (int ks = 0; ks < 4; ++ks){
            int g = ks * 4 + lk;
            int gs = g ^ (brow & 7);
            short8 bfrag = *(const short8*)&Wl[brow * 128 + gs * 8];
            acc[ct] = __builtin_amdgcn_mfma_f32_16x16x32_bf16(afrag[ks], bfrag, acc[ct], 0, 0, 0);
        }
    }
    float ps[H][4], pd[H][4];
#pragma unroll
    for (int hh = 0; hh < H; ++hh)
#pragma unroll
        for (int j = 0; j < 4; ++j){ ps[hh][j] = 0.f; pd[hh][j] = 0.f; }
#pragma unroll
    for (int ct = 0; ct < NCT; ++ct){
        int col = ct * 16 + lr;
        int hh = ct / CPH;
        float asv = atts[col], adv = attd[col];
#pragma unroll
        for (int j = 0; j < 4; ++j){
            float v = acc[ct][j];
            long node = base + wid * 16 + lk * 4 + j;
            if (node < N) h[node * OUT + col] = f2bf(v);
            ps[hh][j] += v * asv;
            pd[hh][j] += v * adv;
        }
    }
#pragma unroll
    for (int m = 1; m < 16; m <<= 1){
#pragma unroll
        for (int hh = 0; hh < H; ++hh)
#pragma unroll
            for (int j = 0; j < 4; ++j){
                ps[hh][j] += __shfl_xor(ps[hh][j], m);
                pd[hh][j] += __shfl_xor(pd[hh][j], m);
            }
    }
    if (lr == 0){
#pragma unroll
        for (int j = 0; j < 4; ++j){
            long node = base + wid * 16 + lk * 4 + j;
            if (node < N){
#pragma unroll
                for (int hh = 0; hh < H; ++hh){
                    as_[node * H + hh] = ps[hh][j];
                    ad_[node * H + hh] = pd[hh][j];
                }
            }
        }
    }
}

// ---------- GAT aggregation (layers 2/3): bf16 h gather ----------
template<int C, int H, int ACT>
__global__ void k_agg(const unsigned short* __restrict__ h, const float* __restrict__ as_,
                      const float* __restrict__ ad_, const int* __restrict__ row_ptr,
                      const int* __restrict__ csr_src, const float* __restrict__ bias,
                      float* __restrict__ out, int N){
    constexpr int CPL = C / 64;
    constexpr int GROUP = C / H;
    int n = blockIdx.x;
    if (n >= N) return;
    int lane = threadIdx.x;
    int hh = (CPL * lane) / GROUP;
    float ad = ad_[n * H + hh];
    int beg = row_ptr[n], end = row_ptr[n + 1];
    float accx = 0.f, accy = 0.f, dn = 0.f;
    const unsigned* h32 = (const unsigned*)h;
    int e = beg;
    for (; e + 2 <= end; e += 2){
        int s0 = csr_src[e], s1 = csr_src[e + 1];
        float a0 = as_[s0 * H + hh], a1 = as_[s1 * H + hh];
        unsigned v0, v1; unsigned short w0, w1;
        if (CPL == 2){ v0 = h32[(long)s0 * 64 + lane]; v1 = h32[(long)s1 * 64 + lane]; }
        else { w0 = h[(long)s0 * 64 + lane]; w1 = h[(long)s1 * 64 + lane]; }
        float p0 = __expf(lrelu_f(a0 + ad));
        float p1 = __expf(lrelu_f(a1 + ad));
        dn += p0 + p1;
        if (CPL == 2){
            accx += p0 * bf_lo(v0) + p1 * bf_lo(v1);
            accy += p0 * bf_hi(v0) + p1 * bf_hi(v1);
        } else {
            accx += p0 * bf2f(w0) + p1 * bf2f(w1);
        }
    }
    if (e < end){
        int s0 = csr_src[e];
        float p0 = __expf(lrelu_f(as_[s0 * H + hh] + ad));
        dn += p0;
        if (CPL == 2){
            unsigned v0 = h32[(long)s0 * 64 + lane];
            accx += p0 * bf_lo(v0); accy += p0 * bf_hi(v0);
        } else {
            accx += p0 * bf2f(h[(long)s0 * 64 + lane]);
        }
    }
    float inv = 1.f / dn;
    if (CPL == 2){
        float vx = accx * inv + bias[2 * lane];
        float vy = accy * inv + bias[2 * lane + 1];
        if (ACT == 1){ vx = elu_f(vx); vy = elu_f(vy); }
        float2 o; o.x = vx; o.y = vy;
        *(float2*)&out[(long)n * C + 2 * lane] = o;
    } else {
        float v = accx * inv + bias[lane];
        if (ACT == 1) v = elu_f(v);
        out[(long)n * C + lane] = v;
    }
}

// ---------- BN stats: no atomics, two-pass ----------
__launch_bounds__(256)
__global__ void k_bn_part(const float* __restrict__ x, int N,
                          float* __restrict__ ps, float* __restrict__ pq){
    __shared__ float4 lsum[256], lsq[256];
    int tid = threadIdx.x;
    int cq = tid & 31;
    int rg = tid >> 5;
    int rpb = (N + gridDim.x - 1) / gridDim.x;
    int lo = blockIdx.x * rpb;
    int hi = lo + rpb; if (hi > N) hi = N;
    float4 s = {0.f, 0.f, 0.f, 0.f}, q = {0.f, 0.f, 0.f, 0.f};
    int r = lo + rg;
    for (; r + 24 < hi; r += 32){
        float4 v0 = *(const float4*)&x[(long)r * 128 + cq * 4];
        float4 v1 = *(const float4*)&x[(long)(r + 8) * 128 + cq * 4];
        float4 v2 = *(const float4*)&x[(long)(r + 16) * 128 + cq * 4];
        float4 v3 = *(const float4*)&x[(long)(r + 24) * 128 + cq * 4];
        s.x += v0.x + v1.x + v2.x + v3.x;
        s.y += v0.y + v1.y + v2.y + v3.y;
        s.z += v0.z + v1.z + v2.z + v3.z;
        s.w += v0.w + v1.w + v2.w + v3.w;
        q.x += v0.x * v0.x + v1.x * v1.x + v2.x * v2.x + v3.x * v3.x;
        q.y += v0.y * v0.y + v1.y * v1.y + v2.y * v2.y + v3.y * v3.y;
        q.z += v0.z * v0.z + v1.z * v1.z + v2.z * v2.z + v3.z * v3.z;
        q.w += v0.w * v0.w + v1.w * v1.w + v2.w * v2.w + v3.w * v3.w;
    }
    for (; r < hi; r += 8){
        float4 v = *(const float4*)&x[(long)r * 128 + cq * 4];
        s.x += v.x; s.y += v.y; s.z += v.z; s.w += v.w;
        q.x += v.x * v.x; q.y += v.y * v.y; q.z += v.z * v.z; q.w += v.w * v.w;
    }
    lsum[tid] = s; lsq[tid] = q;
    __syncthreads();
    for (int o = 4; o > 0; o >>= 1){
        if (rg < o){
            float4 s2 = lsum[tid + o * 32], q2 = lsq[tid + o * 32];
            s.x += s2.x; s.y += s2.y; s.z += s2.z; s.w += s2.w;
            q.x += q2.x; q.y += q2.y; q.z += q2.z; q.w += q2.w;
            lsum[tid] = s; lsq[tid] = q;
        }
        __syncthreads();
    }
    if (rg == 0){
        *(float4*)&ps[(long)blockIdx.x * 128 + cq * 4] = s;
        *(float4*)&pq[(long)blockIdx.x * 128 + cq * 4] = q;
    }
}

__launch_bounds__(1024)
__global__ void k_bn_fin(const float* __restrict__ ps, const float* __restrict__ pq, int PB,
                         const float* __restrict__ g, const float* __restrict__ be,
                         float invN, float* __restrict__ cs, float* __restrict__ cb){
    __shared__ float sh_s[1024], sh_q[1024];
    int tid = threadIdx.x;
    int c = tid & 127, sl = tid >> 7;
    float s = 0.f, q = 0.f;
    for (int b = sl; b < PB; b += 8){
        s += ps[(long)b * 128 + c];
        q += pq[(long)b * 128 + c];
    }
    sh_s[tid] = s; sh_q[tid] = q;
    __syncthreads();
    for (int o = 4; o > 0; o >>= 1){
        if (sl < o){
            s += sh_s[tid + o * 128]; q += sh_q[tid + o * 128];
            sh_s[tid] = s; sh_q[tid] = q;
        }
        __syncthreads();
    }
    if (sl == 0){
        float mu = s * invN;
        float var = q * invN - mu * mu;
        float sc = g[c] * rsqrtf(var + BN_EPS);
        cs[c] = sc;
        cb[c] = be[c] - mu * sc;
    }
}

// ---------- pooling ----------
__global__ void k_pool_part(const float* __restrict__ x, const int* __restrict__ gp,
                            float* __restrict__ psum, unsigned* __restrict__ pmax){
    constexpr int S = 16;
    __shared__ float ssum[256], smax[256];
    int g = blockIdx.y;
    int split = blockIdx.x;
    int tid = threadIdx.x;
    int c = tid & 63, sub = tid >> 6;
    int beg = gp[g], end = gp[g + 1];
    int len = end - beg;
    int chunk = (len + S - 1) / S;
    int lo = beg + split * chunk;
    int hi = lo + chunk; if (hi > end) hi = end;
    if (lo >= hi) return;
    float s = 0.f, mx = -1e30f;
    for (int i = lo + sub; i < hi; i += 4){
        float v = x[(long)i * 64 + c];
        s += v; mx = fmaxf(mx, v);
    }
    ssum[tid] = s; smax[tid] = mx;
    __syncthreads();
    if (tid < 64){
        for (int k = 1; k < 4; ++k){ s += ssum[tid + 64 * k]; mx = fmaxf(mx, smax[tid + 64 * k]); }
        atomicAdd(&psum[g * 64 + c], s);
        atomicMax(&pmax[g * 64 + c], enc_f(mx));
    }
}

__global__ void k_pool_fin(const float* __restrict__ psum, const unsigned* __restrict__ pmax,
                           const int* __restrict__ gp, float* __restrict__ out){
    int g = blockIdx.x;
    int c = threadIdx.x;
    int cnt = gp[g + 1] - gp[g];
    float mean = (cnt > 0) ? psum[g * 64 + c] / (float)cnt : 0.f;
    float mx   = (cnt > 0) ? dec_f(pmax[g * 64 + c]) : 0.f;
    out[g * 128 + c]      = mean;
    out[g * 128 + 64 + c] = mx;
}

extern "C" void kernel_launch(void* const* d_in, const int* in_sizes, int n_in,
                              void* d_out, int out_size, void* d_ws, size_t ws_size,
                              hipStream_t stream){
    const float* x   = (const float*)d_in[0];
    const int*   ei  = (const int*)d_in[1];
    const int*   bat = (const int*)d_in[2];
    const float* W1  = (const float*)d_in[3];
    const float* a1s = (const float*)d_in[4];
    const float* a1d = (const float*)d_in[5];
    const float* b1  = (const float*)d_in[6];
    const float* g1  = (const float*)d_in[7];
    const float* be1 = (const float*)d_in[8];
    const float* W2  = (const float*)d_in[9];
    const float* a2s = (const float*)d_in[10];
    const float* a2d = (const float*)d_in[11];
    const float* b2  = (const float*)d_in[12];
    const float* g2  = (const float*)d_in[13];
    const float* be2 = (const float*)d_in[14];
    const float* W3  = (const float*)d_in[15];
    const float* a3s = (const float*)d_in[16];
    const float* a3d = (const float*)d_in[17];
    const float* b3  = (const float*)d_in[18];
    float* out = (float*)d_out;

    int N  = in_sizes[2];        // 50000
    int E0 = in_sizes[1] / 2;    // 600000
    int E  = E0 + N;
    const int G = 64;
    int P  = (N + 255) / 256;
    const int PB = 512;

    char* ws = (char*)d_ws;
    size_t off = 0;
    auto alloc = [&](size_t bytes) -> char* {
        char* p = ws + off;
        off += (bytes + 255) & ~(size_t)255;
        return p;
    };
    // --- zero-init region ---
    int*      counts  = (int*)alloc((size_t)N * 4);
    int*      cursor  = (int*)alloc((size_t)N * 4);
    float*    psum    = (float*)alloc((size_t)G * 64 * 4);
    unsigned* pmax    = (unsigned*)alloc((size_t)G * 64 * 4);
    size_t zero_bytes = off;
    // --- rest ---
    int*   part    = (int*)alloc(256 * 4);
    int*   row_ptr = (int*)alloc((size_t)(N + 1) * 4);
    int*   csr     = (int*)alloc((size_t)E * 4);
    int*   gp      = (int*)alloc((size_t)(G + 1) * 4);
    float* as_buf  = (float*)alloc((size_t)N * 4 * 4);
    float* ad_buf  = (float*)alloc((size_t)N * 4 * 4);
    float* coefs   = (float*)alloc(128 * 4);
    float* coefb   = (float*)alloc(128 * 4);
    float* u_s     = (float*)alloc(20 * 4);
    float* u_d     = (float*)alloc(20 * 4);
    float* bn_ps   = (float*)alloc((size_t)PB * 128 * 4);
    float* bn_pq   = (float*)alloc((size_t)PB * 128 * 4);
    unsigned short* wt2 = (unsigned short*)alloc(128 * 128 * 2);
    unsigned short* wt3 = (unsigned short*)alloc(64 * 128 * 2);
    unsigned short* hbuf = (unsigned short*)alloc((size_t)N * 128 * 2);
    float* xcur    = (float*)alloc((size_t)N * 128 * 4);

    hipMemsetAsync(ws, 0, zero_bytes, stream);

    int Bc = (E + 255) / 256, Bg = (N + 255) / 256;
    k_prep<<<Bc + Bg + 96 + 1, 256, 0, stream>>>(ei, E0, N, Bc, Bg, bat, G, counts, gp,
                                                 W1, a1s, a1d, W2, W3, wt2, wt3, u_s, u_d);
    k_scan_part<<<P, 256, 0, stream>>>(counts, N, part);
    k_scan_write<<<P, 256, 0, stream>>>(counts, part, N, row_ptr);
    k_scatter<<<(E + 255) / 256, 256, 0, stream>>>(ei, E0, N, row_ptr, cursor, csr);

    // layer 1: rank-5 commuted GAT (edge loop over 5-vectors only)
    k_l1<<<(N + 15) / 16, 256, 0, stream>>>(x, W1, u_s, u_d, row_ptr, csr, b1, xcur, N);
    k_bn_part<<<PB, 256, 0, stream>>>(xcur, N, bn_ps, bn_pq);
    k_bn_fin<<<1, 1024, 0, stream>>>(bn_ps, bn_pq, PB, g1, be1, 1.f / N, coefs, coefb);

    // layer 2: 128 -> 128 (4 heads), MFMA, BN1+ELU fused into X staging
    k_gemm_mfma<128, 4, true><<<(N + 63) / 64, 256, 0, stream>>>(
        xcur, wt2, a2s, a2d, coefs, coefb, hbuf, as_buf, ad_buf, N);
    k_agg<128, 4, 0><<<N, 64, 0, stream>>>(hbuf, as_buf, ad_buf, row_ptr, csr, b2, xcur, N);
    k_bn_part<<<PB, 256, 0, stream>>>(xcur, N, bn_ps, bn_pq);
    k_bn_fin<<<1, 1024, 0, stream>>>(bn_ps, bn_pq, PB, g2, be2, 1.f / N, coefs, coefb);

    // layer 3: 128 -> 64 (1 head), MFMA, BN2+ELU fused into X staging, ELU in agg
    k_gemm_mfma<64, 1, true><<<(N + 63) / 64, 256, 0, stream>>>(
        xcur, wt3, a3s, a3d, coefs, coefb, hbuf, as_buf, ad_buf, N);
    k_agg<64, 1, 1><<<N, 64, 0, stream>>>(hbuf, as_buf, ad_buf, row_ptr, csr, b3, xcur, N);

    // pooling
    {
        dim3 grid(16, G);
        k_pool_part<<<grid, 256, 0, stream>>>(xcur, gp, psum, pmax);
        k_pool_fin<<<G, 64, 0, stream>>>(psum, pmax, gp, out);
    }
}

// Round 12
// 233.130 us; speedup vs baseline: 1.6873x; 1.0400x over previous
//
#include <hip/hip_runtime.h>
#include <math.h>

#define NEG_SLOPE 0.2f
#define BN_EPS 1e-5f

typedef __attribute__((ext_vector_type(8))) short short8;     // 8 bf16 (4 VGPRs)
typedef __attribute__((ext_vector_type(4))) float f32x4;

__device__ __forceinline__ float lrelu_f(float x){ return x > 0.f ? x : NEG_SLOPE * x; }
__device__ __forceinline__ float elu_f(float x){ return x > 0.f ? x : __expf(x) - 1.f; }

__device__ __forceinline__ unsigned short f2bf(float f){
    unsigned u = __float_as_uint(f);
    return (unsigned short)((u + 0x7fffu + ((u >> 16) & 1u)) >> 16);
}
__device__ __forceinline__ float bf_lo(unsigned v){ return __uint_as_float(v << 16); }
__device__ __forceinline__ float bf_hi(unsigned v){ return __uint_as_float(v & 0xffff0000u); }
__device__ __forceinline__ float bf2f(unsigned short b){ return __uint_as_float((unsigned)b << 16); }

__device__ __forceinline__ unsigned enc_f(float x){
    unsigned b = __float_as_uint(x);
    return (b & 0x80000000u) ? ~b : (b | 0x80000000u);
}
__device__ __forceinline__ float dec_f(unsigned u){
    return __uint_as_float((u & 0x80000000u) ? (u & 0x7FFFFFFFu) : ~u);
}

// ---------- fused prep: edge-count + graph_ptr + W2/W3 bf16-transpose + u-vectors ----------
__global__ void k_prep(const int* __restrict__ ei, int E0, int N, int Bc, int Bg,
                       const int* __restrict__ batch, int G,
                       int* __restrict__ counts, int* __restrict__ gp,
                       const float* __restrict__ W1, const float* __restrict__ a1s,
                       const float* __restrict__ a1d,
                       const float* __restrict__ W2, const float* __restrict__ W3,
                       unsigned short* __restrict__ wt2, unsigned short* __restrict__ wt3,
                       float* __restrict__ u_s, float* __restrict__ u_d){
    int b = blockIdx.x, tid = threadIdx.x;
    if (b < Bc){
        int i = b * 256 + tid, tot = E0 + N;
        if (i < tot){
            int dst = (i < E0) ? ei[E0 + i] : (i - E0);
            atomicAdd(&counts[dst], 1);
        }
    } else if (b < Bc + Bg){
        int i = (b - Bc) * 256 + tid;
        if (i < N){
            int bb = batch[i];
            if (i == 0){ for (int g = 0; g <= bb; ++g) gp[g] = 0; }
            else { int pb = batch[i - 1]; for (int g = pb + 1; g <= bb; ++g) gp[g] = i; }
            if (i == N - 1){ for (int g = bb + 1; g <= G; ++g) gp[g] = N; }
        }
    } else if (b < Bc + Bg + 96){
        int i = (b - Bc - Bg) * 256 + tid;   // 0..24575
        if (i < 128 * 128){
            int k = i / 128, c = i % 128;
            wt2[c * 128 + k] = f2bf(W2[i]);
        } else if (i < 128 * 128 + 128 * 64){
            int j = i - 128 * 128;
            int k = j / 64, c = j % 64;
            wt3[c * 128 + k] = f2bf(W3[j]);
        }
    } else {
        // u_s[k*4+hh] = sum_j W1[k][hh*32+j] * a1s[hh][j]  (and u_d with a1d)
        if (tid < 40){
            int t2 = tid % 20;
            int k = t2 / 4, hh = t2 % 4;
            const float* att = (tid < 20) ? a1s : a1d;
            float s = 0.f;
            for (int j = 0; j < 32; ++j) s += W1[k * 128 + hh * 32 + j] * att[hh * 32 + j];
            if (tid < 20) u_s[k * 4 + hh] = s; else u_d[k * 4 + hh] = s;
        }
    }
}

// ---------- scan ----------
__global__ void k_scan_part(const int* __restrict__ counts, int n, int* __restrict__ part){
    __shared__ int sh[256];
    int tid = threadIdx.x;
    int i = blockIdx.x * 256 + tid;
    int v = (i < n) ? counts[i] : 0;
    sh[tid] = v;
    __syncthreads();
    for (int o = 128; o > 0; o >>= 1){
        if (tid < o) sh[tid] += sh[tid + o];
        __syncthreads();
    }
    if (tid == 0) part[blockIdx.x] = sh[0];
}

__global__ void k_scan_write(const int* __restrict__ counts, const int* __restrict__ part,
                             int n, int* __restrict__ row_ptr){
    __shared__ int sh[256], rsh[256];
    __shared__ int offs;
    int tid = threadIdx.x, bid = blockIdx.x;
    int po = 0;
    for (int j = tid; j < bid; j += 256) po += part[j];
    rsh[tid] = po;
    __syncthreads();
    for (int o = 128; o > 0; o >>= 1){
        if (tid < o) rsh[tid] += rsh[tid + o];
        __syncthreads();
    }
    if (tid == 0) offs = rsh[0];
    __syncthreads();
    int i = bid * 256 + tid;
    int v = (i < n) ? counts[i] : 0;
    sh[tid] = v;
    __syncthreads();
    for (int o = 1; o < 256; o <<= 1){
        int t = (tid >= o) ? sh[tid - o] : 0;
        __syncthreads();
        sh[tid] += t;
        __syncthreads();
    }
    if (i < n) row_ptr[i] = offs + sh[tid] - v;
    if (bid == gridDim.x - 1 && tid == 255) row_ptr[n] = offs + sh[255];
}

__global__ void k_scatter(const int* __restrict__ ei, int E0, int N,
                          const int* __restrict__ row_ptr, int* __restrict__ cursor,
                          int* __restrict__ csr_src){
    int i = blockIdx.x * blockDim.x + threadIdx.x;
    int tot = E0 + N;
    if (i >= tot) return;
    int src, dst;
    if (i < E0){ src = ei[i]; dst = ei[E0 + i]; } else { src = dst = i - E0; }
    int pos = atomicAdd(&cursor[dst], 1);
    csr_src[row_ptr[dst] + pos] = src;
}

// ---------- layer-1 fused GAT via rank-5 commutation; bf16 output ----------
__launch_bounds__(256)
__global__ void k_l1(const float* __restrict__ X, const float* __restrict__ W1,
                     const float* __restrict__ u_s, const float* __restrict__ u_d,
                     const int* __restrict__ row_ptr, const int* __restrict__ csr_src,
                     const float* __restrict__ bias, unsigned short* __restrict__ out, int N){
    __shared__ float Wl[5 * 128];
    int tid = threadIdx.x;
    for (int i = tid; i < 5 * 128; i += 256) Wl[i] = W1[i];
    __syncthreads();
    int grp = tid >> 4, ln = tid & 15;
    int hh = ln >> 2, sl = ln & 3;
    long n = (long)blockIdx.x * 16 + grp;
    if (n >= N) return;
    float us[5], ud[5];
#pragma unroll
    for (int k = 0; k < 5; ++k){ us[k] = u_s[k * 4 + hh]; ud[k] = u_d[k * 4 + hh]; }
    float ad = 0.f;
#pragma unroll
    for (int k = 0; k < 5; ++k) ad += X[n * 5 + k] * ud[k];
    int beg = row_ptr[n], end = row_ptr[n + 1];
    float y0 = 0.f, y1 = 0.f, y2 = 0.f, y3 = 0.f, y4 = 0.f, dn = 0.f;
    for (int e = beg + sl; e < end; e += 4){
        long s = csr_src[e];
        float x0 = X[s * 5 + 0], x1 = X[s * 5 + 1], x2 = X[s * 5 + 2],
              x3 = X[s * 5 + 3], x4 = X[s * 5 + 4];
        float as = x0 * us[0] + x1 * us[1] + x2 * us[2] + x3 * us[3] + x4 * us[4];
        float p = __expf(lrelu_f(as + ad));
        dn += p;
        y0 += p * x0; y1 += p * x1; y2 += p * x2; y3 += p * x3; y4 += p * x4;
    }
#pragma unroll
    for (int m = 1; m < 4; m <<= 1){
        y0 += __shfl_xor(y0, m); y1 += __shfl_xor(y1, m); y2 += __shfl_xor(y2, m);
        y3 += __shfl_xor(y3, m); y4 += __shfl_xor(y4, m); dn += __shfl_xor(dn, m);
    }
    float inv = 1.f / dn;
    y0 *= inv; y1 *= inv; y2 *= inv; y3 *= inv; y4 *= inv;
    int c0 = ln * 8;
    const float4* Wl4 = (const float4*)Wl;
    float4 oa, ob;
    {
        float4 w0a = Wl4[0 * 32 + ln * 2], w0b = Wl4[0 * 32 + ln * 2 + 1];
        float4 w1a = Wl4[1 * 32 + ln * 2], w1b = Wl4[1 * 32 + ln * 2 + 1];
        float4 w2a = Wl4[2 * 32 + ln * 2], w2b = Wl4[2 * 32 + ln * 2 + 1];
        float4 w3a = Wl4[3 * 32 + ln * 2], w3b = Wl4[3 * 32 + ln * 2 + 1];
        float4 w4a = Wl4[4 * 32 + ln * 2], w4b = Wl4[4 * 32 + ln * 2 + 1];
        oa.x = y0*w0a.x + y1*w1a.x + y2*w2a.x + y3*w3a.x + y4*w4a.x + bias[c0 + 0];
        oa.y = y0*w0a.y + y1*w1a.y + y2*w2a.y + y3*w3a.y + y4*w4a.y + bias[c0 + 1];
        oa.z = y0*w0a.z + y1*w1a.z + y2*w2a.z + y3*w3a.z + y4*w4a.z + bias[c0 + 2];
        oa.w = y0*w0a.w + y1*w1a.w + y2*w2a.w + y3*w3a.w + y4*w4a.w + bias[c0 + 3];
        ob.x = y0*w0b.x + y1*w1b.x + y2*w2b.x + y3*w3b.x + y4*w4b.x + bias[c0 + 4];
        ob.y = y0*w0b.y + y1*w1b.y + y2*w2b.y + y3*w3b.y + y4*w4b.y + bias[c0 + 5];
        ob.z = y0*w0b.z + y1*w1b.z + y2*w2b.z + y3*w3b.z + y4*w4b.z + bias[c0 + 6];
        ob.w = y0*w0b.w + y1*w1b.w + y2*w2b.w + y3*w3b.w + y4*w4b.w + bias[c0 + 7];
    }
    uint4 o;
    o.x = (unsigned)f2bf(oa.x) | ((unsigned)f2bf(oa.y) << 16);
    o.y = (unsigned)f2bf(oa.z) | ((unsigned)f2bf(oa.w) << 16);
    o.z = (unsigned)f2bf(ob.x) | ((unsigned)f2bf(ob.y) << 16);
    o.w = (unsigned)f2bf(ob.z) | ((unsigned)f2bf(ob.w) << 16);
    *(uint4*)&out[n * 128 + c0] = o;
}

// ---------- MFMA GEMM (IN=128 bf16 -> OUT, H heads), fused BN+ELU on X, fp32 acc ----------
template<int OUT, int H, bool BN>
__launch_bounds__(256)
__global__ void k_gemm_mfma(const unsigned short* __restrict__ X, const unsigned short* __restrict__ Wt,
                            const float* __restrict__ atts, const float* __restrict__ attd,
                            const float* __restrict__ coefs, const float* __restrict__ coefb,
                            unsigned short* __restrict__ h, float* __restrict__ as_,
                            float* __restrict__ ad_, int N){
    constexpr int TM  = 64;
    constexpr int NCT = OUT / 16;
    constexpr int CPH = NCT / H;
    __shared__ unsigned short Xl[TM * 128];
    __shared__ unsigned short Wl[OUT * 128];
    int tid = threadIdx.x;
    long base = (long)blockIdx.x * TM;

    for (int i = tid; i < OUT * 16; i += 256){
        int r = i >> 4, g = i & 15;
        uint4 v = *(const uint4*)&Wt[r * 128 + g * 8];
        int gs = g ^ (r & 7);
        *(uint4*)&Wl[r * 128 + gs * 8] = v;
    }
    for (int i = tid; i < TM * 16; i += 256){
        int r = i >> 4, g = i & 15;
        long node = base + r;
        uint4 o;
        if (node < N){
            uint4 raw = *(const uint4*)&X[node * 128 + g * 8];
            float f[8];
            f[0] = bf_lo(raw.x); f[1] = bf_hi(raw.x);
            f[2] = bf_lo(raw.y); f[3] = bf_hi(raw.y);
            f[4] = bf_lo(raw.z); f[5] = bf_hi(raw.z);
            f[6] = bf_lo(raw.w); f[7] = bf_hi(raw.w);
#pragma unroll
            for (int j = 0; j < 8; ++j){
                float v = f[j];
                if (BN) v = elu_f(fmaf(v, coefs[g * 8 + j], coefb[g * 8 + j]));
                f[j] = v;
            }
            o.x = (unsigned)f2bf(f[0]) | ((unsigned)f2bf(f[1]) << 16);
            o.y = (unsigned)f2bf(f[2]) | ((unsigned)f2bf(f[3]) << 16);
            o.z = (unsigned)f2bf(f[4]) | ((unsigned)f2bf(f[5]) << 16);
            o.w = (unsigned)f2bf(f[6]) | ((unsigned)f2bf(f[7]) << 16);
        } else {
            o.x = o.y = o.z = o.w = 0u;
        }
        int gs = g ^ (r & 7);
        *(uint4*)&Xl[r * 128 + gs * 8] = o;
    }
    __syncthreads();

    int wid = tid >> 6;
    int lane = tid & 63;
    int lr = lane & 15, lk = lane >> 4;

    short8 afrag[4];
    int arow = wid * 16 + lr;
#pragma unroll
    for (int ks = 0; ks < 4; ++ks){
        int g = ks * 4 + lk;
        int gs = g ^ (arow & 7);
        afrag[ks] = *(const short8*)&Xl[arow * 128 + gs * 8];
    }
    f32x4 acc[NCT];
#pragma unroll
    for (int ct = 0; ct < NCT; ++ct) acc[ct] = (f32x4){0.f, 0.f, 0.f, 0.f};
#pragma unroll
    for (int ct = 0; ct < NCT; ++ct){
        int brow = ct * 16 + lr;
#pragma unroll
        for (int ks = 0; ks < 4; ++ks){
            int g = ks * 4 + lk;
            int gs = g ^ (brow & 7);
            short8 bfrag = *(const short8*)&Wl[brow * 128 + gs * 8];
            acc[ct] = __builtin_amdgcn_mfma_f32_16x16x32_bf16(afrag[ks], bfrag, acc[ct], 0, 0, 0);
        }
    }
    float ps[H][4], pd[H][4];
#pragma unroll
    for (int hh = 0; hh < H; ++hh)
#pragma unroll
        for (int j = 0; j < 4; ++j){ ps[hh][j] = 0.f; pd[hh][j] = 0.f; }
#pragma unroll
    for (int ct = 0; ct < NCT; ++ct){
        int col = ct * 16 + lr;
        int hh = ct / CPH;
        float asv = atts[col], adv = attd[col];
#pragma unroll
        for (int j = 0; j < 4; ++j){
            float v = acc[ct][j];
            long node = base + wid * 16 + lk * 4 + j;
            if (node < N) h[node * OUT + col] = f2bf(v);
            ps[hh][j] += v * asv;
            pd[hh][j] += v * adv;
        }
    }
#pragma unroll
    for (int m = 1; m < 16; m <<= 1){
#pragma unroll
        for (int hh = 0; hh < H; ++hh)
#pragma unroll
            for (int j = 0; j < 4; ++j){
                ps[hh][j] += __shfl_xor(ps[hh][j], m);
                pd[hh][j] += __shfl_xor(pd[hh][j], m);
            }
    }
    if (lr == 0){
#pragma unroll
        for (int j = 0; j < 4; ++j){
            long node = base + wid * 16 + lk * 4 + j;
            if (node < N){
#pragma unroll
                for (int hh = 0; hh < H; ++hh){
                    as_[node * H + hh] = ps[hh][j];
                    ad_[node * H + hh] = pd[hh][j];
                }
            }
        }
    }
}

// ---------- GAT aggregation (layers 2/3): bf16 h gather, bf16 output ----------
template<int C, int H, int ACT>
__global__ void k_agg(const unsigned short* __restrict__ h, const float* __restrict__ as_,
                      const float* __restrict__ ad_, const int* __restrict__ row_ptr,
                      const int* __restrict__ csr_src, const float* __restrict__ bias,
                      unsigned short* __restrict__ out, int N){
    constexpr int CPL = C / 64;
    constexpr int GROUP = C / H;
    int n = blockIdx.x;
    if (n >= N) return;
    int lane = threadIdx.x;
    int hh = (CPL * lane) / GROUP;
    float ad = ad_[n * H + hh];
    int beg = row_ptr[n], end = row_ptr[n + 1];
    float accx = 0.f, accy = 0.f, dn = 0.f;
    const unsigned* h32 = (const unsigned*)h;
    int e = beg;
    for (; e + 2 <= end; e += 2){
        int s0 = csr_src[e], s1 = csr_src[e + 1];
        float a0 = as_[s0 * H + hh], a1 = as_[s1 * H + hh];
        unsigned v0, v1; unsigned short w0, w1;
        if (CPL == 2){ v0 = h32[(long)s0 * 64 + lane]; v1 = h32[(long)s1 * 64 + lane]; }
        else { w0 = h[(long)s0 * 64 + lane]; w1 = h[(long)s1 * 64 + lane]; }
        float p0 = __expf(lrelu_f(a0 + ad));
        float p1 = __expf(lrelu_f(a1 + ad));
        dn += p0 + p1;
        if (CPL == 2){
            accx += p0 * bf_lo(v0) + p1 * bf_lo(v1);
            accy += p0 * bf_hi(v0) + p1 * bf_hi(v1);
        } else {
            accx += p0 * bf2f(w0) + p1 * bf2f(w1);
        }
    }
    if (e < end){
        int s0 = csr_src[e];
        float p0 = __expf(lrelu_f(as_[s0 * H + hh] + ad));
        dn += p0;
        if (CPL == 2){
            unsigned v0 = h32[(long)s0 * 64 + lane];
            accx += p0 * bf_lo(v0); accy += p0 * bf_hi(v0);
        } else {
            accx += p0 * bf2f(h[(long)s0 * 64 + lane]);
        }
    }
    float inv = 1.f / dn;
    if (CPL == 2){
        float vx = accx * inv + bias[2 * lane];
        float vy = accy * inv + bias[2 * lane + 1];
        if (ACT == 1){ vx = elu_f(vx); vy = elu_f(vy); }
        ((unsigned*)out)[(long)n * 64 + lane] =
            (unsigned)f2bf(vx) | ((unsigned)f2bf(vy) << 16);
    } else {
        float v = accx * inv + bias[lane];
        if (ACT == 1) v = elu_f(v);
        out[(long)n * 64 + lane] = f2bf(v);
    }
}

// ---------- BN stats from bf16 x: no atomics, two-pass ----------
__launch_bounds__(256)
__global__ void k_bn_part(const unsigned short* __restrict__ x, int N,
                          float* __restrict__ ps, float* __restrict__ pq){
    __shared__ float ls[256 * 8], lq[256 * 8];
    int tid = threadIdx.x;
    int cg = tid & 15;           // channel octet: channels cg*8..cg*8+7
    int rg = tid >> 4;           // 16 row groups
    int rpb = (N + gridDim.x - 1) / gridDim.x;
    int lo = blockIdx.x * rpb;
    int hi = lo + rpb; if (hi > N) hi = N;
    float s[8], q[8];
#pragma unroll
    for (int j = 0; j < 8; ++j){ s[j] = 0.f; q[j] = 0.f; }
    int r = lo + rg;
    for (; r + 16 < hi; r += 32){
        uint4 va = *(const uint4*)&x[(long)r * 128 + cg * 8];
        uint4 vb = *(const uint4*)&x[(long)(r + 16) * 128 + cg * 8];
        float fa[8], fb[8];
        fa[0]=bf_lo(va.x); fa[1]=bf_hi(va.x); fa[2]=bf_lo(va.y); fa[3]=bf_hi(va.y);
        fa[4]=bf_lo(va.z); fa[5]=bf_hi(va.z); fa[6]=bf_lo(va.w); fa[7]=bf_hi(va.w);
        fb[0]=bf_lo(vb.x); fb[1]=bf_hi(vb.x); fb[2]=bf_lo(vb.y); fb[3]=bf_hi(vb.y);
        fb[4]=bf_lo(vb.z); fb[5]=bf_hi(vb.z); fb[6]=bf_lo(vb.w); fb[7]=bf_hi(vb.w);
#pragma unroll
        for (int j = 0; j < 8; ++j){
            s[j] += fa[j] + fb[j];
            q[j] += fa[j] * fa[j] + fb[j] * fb[j];
        }
    }
    for (; r < hi; r += 16){
        uint4 va = *(const uint4*)&x[(long)r * 128 + cg * 8];
        float fa[8];
        fa[0]=bf_lo(va.x); fa[1]=bf_hi(va.x); fa[2]=bf_lo(va.y); fa[3]=bf_hi(va.y);
        fa[4]=bf_lo(va.z); fa[5]=bf_hi(va.z); fa[6]=bf_lo(va.w); fa[7]=bf_hi(va.w);
#pragma unroll
        for (int j = 0; j < 8; ++j){ s[j] += fa[j]; q[j] += fa[j] * fa[j]; }
    }
#pragma unroll
    for (int j = 0; j < 8; ++j){ ls[tid * 8 + j] = s[j]; lq[tid * 8 + j] = q[j]; }
    __syncthreads();
    for (int o = 8; o > 0; o >>= 1){
        if (rg < o){
#pragma unroll
            for (int j = 0; j < 8; ++j){
                s[j] += ls[(tid + o * 16) * 8 + j];
                q[j] += lq[(tid + o * 16) * 8 + j];
                ls[tid * 8 + j] = s[j]; lq[tid * 8 + j] = q[j];
            }
        }
        __syncthreads();
    }
    if (rg == 0){
#pragma unroll
        for (int j = 0; j < 8; ++j){
            ps[(long)blockIdx.x * 128 + cg * 8 + j] = s[j];
            pq[(long)blockIdx.x * 128 + cg * 8 + j] = q[j];
        }
    }
}

__launch_bounds__(1024)
__global__ void k_bn_fin(const float* __restrict__ ps, const float* __restrict__ pq, int PB,
                         const float* __restrict__ g, const float* __restrict__ be,
                         float invN, float* __restrict__ cs, float* __restrict__ cb){
    __shared__ float sh_s[1024], sh_q[1024];
    int tid = threadIdx.x;
    int c = tid & 127, sl = tid >> 7;
    float s = 0.f, q = 0.f;
    for (int b = sl; b < PB; b += 8){
        s += ps[(long)b * 128 + c];
        q += pq[(long)b * 128 + c];
    }
    sh_s[tid] = s; sh_q[tid] = q;
    __syncthreads();
    for (int o = 4; o > 0; o >>= 1){
        if (sl < o){
            s += sh_s[tid + o * 128]; q += sh_q[tid + o * 128];
            sh_s[tid] = s; sh_q[tid] = q;
        }
        __syncthreads();
    }
    if (sl == 0){
        float mu = s * invN;
        float var = q * invN - mu * mu;
        float sc = g[c] * rsqrtf(var + BN_EPS);
        cs[c] = sc;
        cb[c] = be[c] - mu * sc;
    }
}

// ---------- pooling over bf16 [N][64] ----------
__global__ void k_pool_part(const unsigned short* __restrict__ x, const int* __restrict__ gp,
                            float* __restrict__ psum, unsigned* __restrict__ pmax){
    constexpr int S = 16;
    __shared__ float2 ssum[256], smax[256];
    int g = blockIdx.y;
    int split = blockIdx.x;
    int tid = threadIdx.x;
    int c2 = tid & 31, sub = tid >> 5;   // 2 channels per lane, 8 row splits
    int beg = gp[g], end = gp[g + 1];
    int len = end - beg;
    int chunk = (len + S - 1) / S;
    int lo = beg + split * chunk;
    int hi = lo + chunk; if (hi > end) hi = end;
    if (lo >= hi) return;   // uniform per block
    float sx = 0.f, sy = 0.f, mx = -1e30f, my = -1e30f;
    const unsigned* xr = (const unsigned*)x;
    for (int i = lo + sub; i < hi; i += 8){
        unsigned v = xr[(long)i * 32 + c2];
        float a = bf_lo(v), b = bf_hi(v);
        sx += a; sy += b;
        mx = fmaxf(mx, a); my = fmaxf(my, b);
    }
    ssum[tid] = make_float2(sx, sy); smax[tid] = make_float2(mx, my);
    __syncthreads();
    for (int o = 4; o > 0; o >>= 1){
        if (sub < o){
            float2 s2 = ssum[tid + o * 32], m2 = smax[tid + o * 32];
            sx += s2.x; sy += s2.y;
            mx = fmaxf(mx, m2.x); my = fmaxf(my, m2.y);
            ssum[tid] = make_float2(sx, sy); smax[tid] = make_float2(mx, my);
        }
        __syncthreads();
    }
    if (sub == 0){
        atomicAdd(&psum[g * 64 + c2 * 2], sx);
        atomicAdd(&psum[g * 64 + c2 * 2 + 1], sy);
        atomicMax(&pmax[g * 64 + c2 * 2], enc_f(mx));
        atomicMax(&pmax[g * 64 + c2 * 2 + 1], enc_f(my));
    }
}

__global__ void k_pool_fin(const float* __restrict__ psum, const unsigned* __restrict__ pmax,
                           const int* __restrict__ gp, float* __restrict__ out){
    int g = blockIdx.x;
    int c = threadIdx.x;
    int cnt = gp[g + 1] - gp[g];
    float mean = (cnt > 0) ? psum[g * 64 + c] / (float)cnt : 0.f;
    float mx   = (cnt > 0) ? dec_f(pmax[g * 64 + c]) : 0.f;
    out[g * 128 + c]      = mean;
    out[g * 128 + 64 + c] = mx;
}

extern "C" void kernel_launch(void* const* d_in, const int* in_sizes, int n_in,
                              void* d_out, int out_size, void* d_ws, size_t ws_size,
                              hipStream_t stream){
    const float* x   = (const float*)d_in[0];
    const int*   ei  = (const int*)d_in[1];
    const int*   bat = (const int*)d_in[2];
    const float* W1  = (const float*)d_in[3];
    const float* a1s = (const float*)d_in[4];
    const float* a1d = (const float*)d_in[5];
    const float* b1  = (const float*)d_in[6];
    const float* g1  = (const float*)d_in[7];
    const float* be1 = (const float*)d_in[8];
    const float* W2  = (const float*)d_in[9];
    const float* a2s = (const float*)d_in[10];
    const float* a2d = (const float*)d_in[11];
    const float* b2  = (const float*)d_in[12];
    const float* g2  = (const float*)d_in[13];
    const float* be2 = (const float*)d_in[14];
    const float* W3  = (const float*)d_in[15];
    const float* a3s = (const float*)d_in[16];
    const float* a3d = (const float*)d_in[17];
    const float* b3  = (const float*)d_in[18];
    float* out = (float*)d_out;

    int N  = in_sizes[2];        // 50000
    int E0 = in_sizes[1] / 2;    // 600000
    int E  = E0 + N;
    const int G = 64;
    int P  = (N + 255) / 256;
    const int PB = 512;

    char* ws = (char*)d_ws;
    size_t off = 0;
    auto alloc = [&](size_t bytes) -> char* {
        char* p = ws + off;
        off += (bytes + 255) & ~(size_t)255;
        return p;
    };
    // --- zero-init region ---
    int*      counts  = (int*)alloc((size_t)N * 4);
    int*      cursor  = (int*)alloc((size_t)N * 4);
    float*    psum    = (float*)alloc((size_t)G * 64 * 4);
    unsigned* pmax    = (unsigned*)alloc((size_t)G * 64 * 4);
    size_t zero_bytes = off;
    // --- rest ---
    int*   part    = (int*)alloc(256 * 4);
    int*   row_ptr = (int*)alloc((size_t)(N + 1) * 4);
    int*   csr     = (int*)alloc((size_t)E * 4);
    int*   gp      = (int*)alloc((size_t)(G + 1) * 4);
    float* as_buf  = (float*)alloc((size_t)N * 4 * 4);
    float* ad_buf  = (float*)alloc((size_t)N * 4 * 4);
    float* coefs   = (float*)alloc(128 * 4);
    float* coefb   = (float*)alloc(128 * 4);
    float* u_s     = (float*)alloc(20 * 4);
    float* u_d     = (float*)alloc(20 * 4);
    float* bn_ps   = (float*)alloc((size_t)PB * 128 * 4);
    float* bn_pq   = (float*)alloc((size_t)PB * 128 * 4);
    unsigned short* wt2 = (unsigned short*)alloc(128 * 128 * 2);
    unsigned short* wt3 = (unsigned short*)alloc(64 * 128 * 2);
    unsigned short* hbuf = (unsigned short*)alloc((size_t)N * 128 * 2);
    unsigned short* xcur = (unsigned short*)alloc((size_t)N * 128 * 2);

    hipMemsetAsync(ws, 0, zero_bytes, stream);

    int Bc = (E + 255) / 256, Bg = (N + 255) / 256;
    k_prep<<<Bc + Bg + 96 + 1, 256, 0, stream>>>(ei, E0, N, Bc, Bg, bat, G, counts, gp,
                                                 W1, a1s, a1d, W2, W3, wt2, wt3, u_s, u_d);
    k_scan_part<<<P, 256, 0, stream>>>(counts, N, part);
    k_scan_write<<<P, 256, 0, stream>>>(counts, part, N, row_ptr);
    k_scatter<<<(E + 255) / 256, 256, 0, stream>>>(ei, E0, N, row_ptr, cursor, csr);

    // layer 1: rank-5 commuted GAT -> bf16 xcur
    k_l1<<<(N + 15) / 16, 256, 0, stream>>>(x, W1, u_s, u_d, row_ptr, csr, b1, xcur, N);
    k_bn_part<<<PB, 256, 0, stream>>>(xcur, N, bn_ps, bn_pq);
    k_bn_fin<<<1, 1024, 0, stream>>>(bn_ps, bn_pq, PB, g1, be1, 1.f / N, coefs, coefb);

    // layer 2: 128 -> 128 (4 heads), MFMA, BN1+ELU fused into X staging
    k_gemm_mfma<128, 4, true><<<(N + 63) / 64, 256, 0, stream>>>(
        xcur, wt2, a2s, a2d, coefs, coefb, hbuf, as_buf, ad_buf, N);
    k_agg<128, 4, 0><<<N, 64, 0, stream>>>(hbuf, as_buf, ad_buf, row_ptr, csr, b2, xcur, N);
    k_bn_part<<<PB, 256, 0, stream>>>(xcur, N, bn_ps, bn_pq);
    k_bn_fin<<<1, 1024, 0, stream>>>(bn_ps, bn_pq, PB, g2, be2, 1.f / N, coefs, coefb);

    // layer 3: 128 -> 64 (1 head), MFMA, BN2+ELU fused into X staging, ELU in agg
    k_gemm_mfma<64, 1, true><<<(N + 63) / 64, 256, 0, stream>>>(
        xcur, wt3, a3s, a3d, coefs, coefb, hbuf, as_buf, ad_buf, N);
    k_agg<64, 1, 1><<<N, 64, 0, stream>>>(hbuf, as_buf, ad_buf, row_ptr, csr, b3, xcur, N);

    // pooling
    {
        dim3 grid(16, G);
        k_pool_part<<<grid, 256, 0, stream>>>(xcur, gp, psum, pmax);
        k_pool_fin<<<G, 64, 0, stream>>>(psum, pmax, gp, out);
    }
}